// Round 3
// baseline (6433.471 us; speedup 1.0000x reference)
//
#include <hip/hip_runtime.h>
#include <hip/hip_bf16.h>

#define B_   32
#define T_   512
#define NN_  16
#define CV_  150
#define D_   512
#define H_   512
#define BT_  16384      // B*T
#define K0_  1024       // 2*D
#define G3H_ 1536       // 3*H
#define NBF_ 160        // 5 * 32
#define WSZ_ 49152      // bf16 elems of swizzled W per block (96 frags * 512)
#define XSLOT_ 16384    // elems per x ring slot (32*512)
#define XRING_ 32
#define HRING_ 8
#define SENT32 0x7f7f7f7fu
#define HCAP 4096
#define XCAP 4096
#define BCAP 65536

using bf16x8 = __attribute__((ext_vector_type(8))) short;
using f32x4  = __attribute__((ext_vector_type(4))) float;
using u32x4  = __attribute__((ext_vector_type(4))) unsigned int;
typedef unsigned long long u64;

__device__ __forceinline__ unsigned short f2bf(float f){
  unsigned int u = __builtin_bit_cast(unsigned int, f);
  u += 0x7fffu + ((u >> 16) & 1u);           // RNE
  return (unsigned short)(u >> 16);
}

__device__ __forceinline__ void store8(unsigned short* p, f32x4 a, f32x4 b){
  union { unsigned short us[8]; u32x4 v; } u;
  u.us[0]=f2bf(a[0]); u.us[1]=f2bf(a[1]); u.us[2]=f2bf(a[2]); u.us[3]=f2bf(a[3]);
  u.us[4]=f2bf(b[0]); u.us[5]=f2bf(b[1]); u.us[6]=f2bf(b[2]); u.us[7]=f2bf(b[3]);
  *(u32x4*)p = u.v;
}

// agent-scope (device-coherent) helpers: relaxed atomics, no fences (proven in r0)
__device__ __forceinline__ u64 ld_coh_u64(const u64* p){
  return __hip_atomic_load(p, __ATOMIC_RELAXED, __HIP_MEMORY_SCOPE_AGENT);
}
__device__ __forceinline__ void st_coh_u32(void* p, unsigned int v){
  __hip_atomic_store((unsigned int*)p, v, __ATOMIC_RELAXED, __HIP_MEMORY_SCOPE_AGENT);
}
__device__ __forceinline__ void st_flag(int* p, int v){
  __hip_atomic_store(p, v, __ATOMIC_RELAXED, __HIP_MEMORY_SCOPE_AGENT);
}
__device__ __forceinline__ int ld_flag(const int* p){
  return __hip_atomic_load(p, __ATOMIC_RELAXED, __HIP_MEMORY_SCOPE_AGENT);
}

__device__ __forceinline__ bool bad64(u64 q){
  return ((unsigned int)q == SENT32) | ((unsigned int)(q >> 32) == SENT32);
}

// ---------------- fp32 -> bf16 weight conversion ----------------
__global__ void convert_bf16(const float* __restrict__ src,
                             unsigned short* __restrict__ dst, int n){
  int i = blockIdx.x * 256 + threadIdx.x;
  if (i < n) dst[i] = f2bf(src[i]);
}

// ---------------- swizzle W into MFMA A-frag layout ----------------
__global__ void prep_wfrag(const float* __restrict__ whh0,
                           const float* __restrict__ whhr,
                           const float* __restrict__ wihr,
                           unsigned short* __restrict__ wsw, int total){
  int idx = blockIdx.x * 256 + threadIdx.x;
  if (idx >= total) return;
  int pos = idx & 511;
  int lam = pos >> 3, e = pos & 7;
  int fr  = idx >> 9;
  int ks  = fr & 31;
  int g   = (fr >> 5) % 3;
  int blk = fr / 96;
  int sub = blk & 31, l = blk >> 5;
  int row = g * 512 + sub * 16 + (lam & 15);
  int k   = (ks & 15) * 32 + (lam >> 4) * 8 + e;
  float v;
  if (l == 0) v = (ks < 16) ? whh0[(size_t)row * H_ + k] : 0.f;
  else {
    const float* w = (ks < 16) ? (whhr + (size_t)(l - 1) * G3H_ * H_)
                               : (wihr + (size_t)(l - 1) * G3H_ * H_);
    v = w[(size_t)row * H_ + k];
  }
  wsw[idx] = f2bf(v);
}

__global__ void prep_bias(const float* __restrict__ bhh0,
                          const float* __restrict__ bihr,
                          const float* __restrict__ bhhr,
                          float* __restrict__ bias_sw, int total){
  int idx = blockIdx.x * 256 + threadIdx.x;
  if (idx >= total) return;
  int q = idx & 3, u = (idx >> 2) & 15, sub = (idx >> 6) & 31, l = idx >> 11;
  int j = sub * 16 + u;
  float v;
  if (l == 0){
    v = (q == 0) ? bhh0[j] : (q == 1) ? bhh0[512 + j] : (q == 2) ? 0.f : bhh0[1024 + j];
  } else {
    const float* bi = bihr + (size_t)(l - 1) * G3H_;
    const float* bh = bhhr + (size_t)(l - 1) * G3H_;
    v = (q == 0) ? bi[j] + bh[j]
      : (q == 1) ? bi[512 + j] + bh[512 + j]
      : (q == 2) ? bi[1024 + j] : bh[1024 + j];
  }
  bias_sw[idx] = v;
}

// ---------------- embeddings ----------------
__global__ __launch_bounds__(64) void emb_kernel(
    const int* __restrict__ note, const int* __restrict__ chord,
    const float* __restrict__ ctab, const float* __restrict__ ntab,
    unsigned short* __restrict__ x0){
  const int bt = blockIdx.x;
  const int tid = threadIdx.x;
  __shared__ int sn[NN_];
  if (tid < NN_) sn[tid] = note[bt * NN_ + tid];
  __syncthreads();
  float alive = 1.f, cnt = 0.f;
  float msk[NN_];
  #pragma unroll
  for (int k = 0; k < NN_; ++k){ if (sn[k] == 0) alive = 0.f; msk[k] = alive; cnt += alive; }
  const float inv = 1.f / fmaxf(cnt, 1.f);
  const int ch = chord[bt];
  const int d0 = tid * 8;
  f32x4 c0 = {0.f,0.f,0.f,0.f}, c1 = {0.f,0.f,0.f,0.f};
  if (ch != 0){
    const float* cp = ctab + (size_t)ch * D_ + d0;
    c0 = *(const f32x4*)cp; c1 = *(const f32x4*)(cp + 4);
  }
  f32x4 s0 = {0.f,0.f,0.f,0.f}, s1 = {0.f,0.f,0.f,0.f};
  #pragma unroll
  for (int k = 0; k < NN_; ++k){
    if (msk[k] != 0.f){
      const float* np = ntab + (size_t)sn[k] * D_ + d0;
      s0 += *(const f32x4*)np;
      s1 += *(const f32x4*)(np + 4);
    }
  }
  s0 *= inv; s1 *= inv;
  unsigned short* o = x0 + (size_t)bt * K0_ + d0;
  store8(o, c0, c1);
  store8(o + D_, s0, s1);
}

// ---------------- bf16 MFMA GEMM:  Y = X[M,K] @ W[N,K]^T + bias ----------------
__global__ __launch_bounds__(256) void gemm_bt(
    const unsigned short* __restrict__ X, const unsigned short* __restrict__ W,
    const float* __restrict__ bias, float* __restrict__ Y,
    int M, int N, int K, int wmode){
  const int lane = threadIdx.x & 63;
  const int wave = threadIdx.x >> 6;
  const int l15 = lane & 15, kq4 = lane >> 4;
  const int m_frag = blockIdx.y * 64 + wave * 16 + l15;
  const int n_base = blockIdx.x * 64;
  f32x4 acc[4] = {{0.f,0.f,0.f,0.f},{0.f,0.f,0.f,0.f},{0.f,0.f,0.f,0.f},{0.f,0.f,0.f,0.f}};
  const unsigned short* xptr = X + (size_t)m_frag * K + kq4 * 8;
  const unsigned short* wptr[4];
  #pragma unroll
  for (int i = 0; i < 4; ++i){
    int n = n_base + i * 16 + l15;
    if (n >= N) n = N - 1;
    wptr[i] = W + (size_t)n * K + kq4 * 8;
  }
  for (int k0 = 0; k0 < K; k0 += 32){
    bf16x8 a = *(const bf16x8*)(xptr + k0);
    #pragma unroll
    for (int i = 0; i < 4; ++i){
      bf16x8 b = *(const bf16x8*)(wptr[i] + k0);
      acc[i] = __builtin_amdgcn_mfma_f32_16x16x32_bf16(a, b, acc[i], 0, 0, 0);
    }
  }
  const int mrow = blockIdx.y * 64 + wave * 16 + kq4 * 4;
  #pragma unroll
  for (int i = 0; i < 4; ++i){
    int n = n_base + i * 16 + l15;
    if (n < N){
      float bv = bias[n];
      #pragma unroll
      for (int r = 0; r < 4; ++r){
        int m = mrow + r;
        float v = acc[i][r] + bv;
        if (wmode == 0) Y[(size_t)m * N + n] = v;
        else            Y[((size_t)(m & (T_-1)) * N + n) * B_ + (m >> 9)] = v;
      }
    }
  }
}

// ---------------- fused 5-layer GRU: sentinel-gated L3 exchange ----------------
// 160 blocks (l=blk>>5, sub=blk&31). No flags on the critical path:
// h ring hT[l][t&7][b][u]: data at slot t+1, sentinel re-arm at slot t+4.
//   Peer skew <=1 step (mutual data dependency); arm drained by the per-step
//   __syncthreads (vmcnt(0)) >=2 steps before any peer data-write to the slot.
// x ring xT[l][t&31][b][u]: data at slot t, re-arm at slot t+16; back-pressure
//   every 4 steps (consumer progress flag) bounds producer <= consumer+8, so
//   re-arm never clobbers unread data and consumers never see stale slots.
// All spins capped small: failure = wrong answer with counters, never a hang.
union Ufrag { u64 q[2]; bf16x8 v; };

__global__ __launch_bounds__(256, 1) void gru_fused(
    const float* __restrict__ xp, const unsigned short* __restrict__ wsw,
    const float* __restrict__ bias_sw, unsigned short* hT,
    unsigned short* xT, unsigned short* xout, int* cprog){
  __shared__ unsigned short w_s[96 * 512];     // 96 KB A-frags
  __shared__ float p_s[2][4][2][2][16][16];    // [pb][r,z,hn,xn][myn][kh][u][b] 16KB

  const int tid = threadIdx.x;
  const int blk = blockIdx.x;
  const int l   = blk >> 5;
  const int sub = blk & 31;

  { // W -> LDS
    const u32x4* src = (const u32x4*)(wsw + (size_t)blk * WSZ_);
    u32x4* dst = (u32x4*)w_s;
    #pragma unroll
    for (int i = 0; i < 24; ++i) dst[tid + 256 * i] = src[tid + 256 * i];
  }
  __syncthreads();

  const int lane = tid & 63, wave = tid >> 6;
  const int l15 = lane & 15, l4 = lane >> 4;
  const int myn = wave >> 1;            // batch 16-group
  const int kh  = wave & 1;             // K-half
  const int myb = (myn << 4) + l15;
  const int fro = (l4 << 3);
  const int khofs = kh * 256;           // element offset of the K-half
  const int khb = kh * 8;               // frag base of the K-half

  const int cb = tid & 31;
  const int cj = (tid >> 5) * 2;
  const int jg = sub * 16 + cj;
  const float* bsp = bias_sw + blk * 64;
  const float br0 = bsp[cj*4+0],     bz0 = bsp[cj*4+1],     bx0 = bsp[cj*4+2],     bn0 = bsp[cj*4+3];
  const float br1 = bsp[(cj+1)*4+0], bz1 = bsp[(cj+1)*4+1], bx1 = bsp[(cj+1)*4+2], bn1 = bsp[(cj+1)*4+3];
  float hres0 = 0.f, hres1 = 0.f;

  unsigned short* hTl = hT + (size_t)l * (HRING_ * 32 * 512);
  unsigned short* xTw = xT + (size_t)(l < 4 ? l : 0) * ((size_t)XRING_ * XSLOT_);
  const unsigned short* xTr = xT + (size_t)(l > 0 ? l - 1 : 0) * ((size_t)XRING_ * XSLOT_);
  const int* bp_own = cprog + (l << 5);          // consumers of my x publish here
  int*       bp_pub = cprog + ((l > 0 ? l - 1 : 0) << 5);

  // xp 2-ahead prefetch registers (layer 0 only)
  float era=0,eza=0,ena=0,era1=0,eza1=0,ena1=0;
  float erb=0,ezb=0,enb=0,erb1=0,ezb1=0,enb1=0;
  if (l == 0){
    { const float* xq = xp + (size_t)0 * (G3H_ * B_) + cb;
      era=xq[(size_t)(0*H_+jg)*B_]; era1=xq[(size_t)(0*H_+jg+1)*B_];
      eza=xq[(size_t)(1*H_+jg)*B_]; eza1=xq[(size_t)(1*H_+jg+1)*B_];
      ena=xq[(size_t)(2*H_+jg)*B_]; ena1=xq[(size_t)(2*H_+jg+1)*B_]; }
    { const float* xq = xp + (size_t)1 * (G3H_ * B_) + cb;
      erb=xq[(size_t)(0*H_+jg)*B_]; erb1=xq[(size_t)(0*H_+jg+1)*B_];
      ezb=xq[(size_t)(1*H_+jg)*B_]; ezb1=xq[(size_t)(1*H_+jg+1)*B_];
      enb=xq[(size_t)(2*H_+jg)*B_]; enb1=xq[(size_t)(2*H_+jg+1)*B_]; }
  }

  for (int t = 0; t < T_; ++t){
    const int pb = t & 1;

    // ---- h(t): sentinel-gated direct loads (full h assembled by 32 peers) ----
    Ufrag hb[8];
    const unsigned short* hf = hTl + (((size_t)(t & HRING_-1) * 32 + myb) << 9) + khofs + fro;
    #pragma unroll
    for (int j = 0; j < 8; ++j){
      const u64* sp = (const u64*)(hf + (j << 5));
      hb[j].q[0] = ld_coh_u64(sp); hb[j].q[1] = ld_coh_u64(sp + 1);
    }
    {
      int itc = 0;
      while (true){
        int nbad = 0;
        #pragma unroll
        for (int j = 0; j < 8; ++j){
          bool bd = bad64(hb[j].q[0]) | bad64(hb[j].q[1]);
          if (__any((int)bd)){
            ++nbad;
            const u64* sp = (const u64*)(hf + (j << 5));
            hb[j].q[0] = ld_coh_u64(sp); hb[j].q[1] = ld_coh_u64(sp + 1);
          }
        }
        if (nbad == 0) break;
        if (++itc > HCAP) break;
      }
    }

    // ---- issue x(t) loads early (polled after h-MFMA) ----
    Ufrag xb[8];
    const unsigned short* xs = nullptr;
    if (l > 0){
      xs = xTr + (size_t)(t & XRING_-1) * XSLOT_ + (size_t)myb * 512 + khofs + fro;
      #pragma unroll
      for (int j = 0; j < 8; ++j){
        const u64* sp = (const u64*)(xs + (j << 5));
        xb[j].q[0] = ld_coh_u64(sp); xb[j].q[1] = ld_coh_u64(sp + 1);
      }
    }

    // ---- producer back-pressure (every 4 steps, off critical path) ----
    if (l < 4 && t && (t & 3) == 0){
      int itc = 0;
      while (true){
        int v = (lane < 32) ? ld_flag(&bp_own[lane]) : 0x7fffffff;
        if (__all(v >= t - 4)) break;
        if (++itc > BCAP) break;
        __builtin_amdgcn_s_sleep(2);
      }
    }

    // ---- h-MFMA (this wave's K-half: 8 frags x {r,z,hn}) ----
    f32x4 accR = {0.f,0.f,0.f,0.f}, accZ = {0.f,0.f,0.f,0.f};
    f32x4 accN = {0.f,0.f,0.f,0.f}, accX = {0.f,0.f,0.f,0.f};
    #pragma unroll
    for (int j = 0; j < 8; ++j){
      bf16x8 b  = hb[j].v;
      bf16x8 a0 = *(const bf16x8*)&w_s[(0 * 32 + khb + j) * 512 + lane * 8];
      bf16x8 a1 = *(const bf16x8*)&w_s[(1 * 32 + khb + j) * 512 + lane * 8];
      bf16x8 a2 = *(const bf16x8*)&w_s[(2 * 32 + khb + j) * 512 + lane * 8];
      accR = __builtin_amdgcn_mfma_f32_16x16x32_bf16(a0, b, accR, 0, 0, 0);
      accZ = __builtin_amdgcn_mfma_f32_16x16x32_bf16(a1, b, accZ, 0, 0, 0);
      accN = __builtin_amdgcn_mfma_f32_16x16x32_bf16(a2, b, accN, 0, 0, 0);
    }

    // ---- x: sentinel poll + x-MFMA ----
    if (l > 0){
      int itc = 0;
      while (true){
        int nbad = 0;
        #pragma unroll
        for (int j = 0; j < 8; ++j){
          bool bd = bad64(xb[j].q[0]) | bad64(xb[j].q[1]);
          if (__any((int)bd)){
            ++nbad;
            const u64* sp = (const u64*)(xs + (j << 5));
            xb[j].q[0] = ld_coh_u64(sp); xb[j].q[1] = ld_coh_u64(sp + 1);
          }
        }
        if (nbad == 0) break;
        if (++itc > XCAP) break;
      }
      #pragma unroll
      for (int j = 0; j < 8; ++j){
        bf16x8 b  = xb[j].v;
        bf16x8 a0 = *(const bf16x8*)&w_s[(0 * 32 + 16 + khb + j) * 512 + lane * 8];
        bf16x8 a1 = *(const bf16x8*)&w_s[(1 * 32 + 16 + khb + j) * 512 + lane * 8];
        bf16x8 a2 = *(const bf16x8*)&w_s[(2 * 32 + 16 + khb + j) * 512 + lane * 8];
        accR = __builtin_amdgcn_mfma_f32_16x16x32_bf16(a0, b, accR, 0, 0, 0);
        accZ = __builtin_amdgcn_mfma_f32_16x16x32_bf16(a1, b, accZ, 0, 0, 0);
        accX = __builtin_amdgcn_mfma_f32_16x16x32_bf16(a2, b, accX, 0, 0, 0);  // xn
      }
    }

    // ---- xp prefetch for t+2 (layer 0) ----
    float erc=0,ezc=0,enc=0,erc1=0,ezc1=0,enc1=0;
    if (l == 0){
      const float* xq = xp + (size_t)((t + 2) & (T_ - 1)) * (G3H_ * B_) + cb;
      erc=xq[(size_t)(0*H_+jg)*B_]; erc1=xq[(size_t)(0*H_+jg+1)*B_];
      ezc=xq[(size_t)(1*H_+jg)*B_]; ezc1=xq[(size_t)(1*H_+jg+1)*B_];
      enc=xq[(size_t)(2*H_+jg)*B_]; enc1=xq[(size_t)(2*H_+jg+1)*B_];
    }

    // ---- partials -> p_s[pb] ----
    #pragma unroll
    for (int r = 0; r < 4; ++r){
      int u = l4 * 4 + r;
      p_s[pb][0][myn][kh][u][l15] = accR[r];
      p_s[pb][1][myn][kh][u][l15] = accZ[r];
      p_s[pb][2][myn][kh][u][l15] = accN[r];
      p_s[pb][3][myn][kh][u][l15] = accX[r];
    }
    __syncthreads();   // also drains all prior-step stores (vmcnt 0)

    // ---- combine ----
    {
      const int nt = cb >> 4, bc = cb & 15;
      float rp0 = p_s[pb][0][nt][0][cj][bc]   + p_s[pb][0][nt][1][cj][bc];
      float rp1 = p_s[pb][0][nt][0][cj+1][bc] + p_s[pb][0][nt][1][cj+1][bc];
      float zp0 = p_s[pb][1][nt][0][cj][bc]   + p_s[pb][1][nt][1][cj][bc];
      float zp1 = p_s[pb][1][nt][0][cj+1][bc] + p_s[pb][1][nt][1][cj+1][bc];
      float hp0 = p_s[pb][2][nt][0][cj][bc]   + p_s[pb][2][nt][1][cj][bc];
      float hp1 = p_s[pb][2][nt][0][cj+1][bc] + p_s[pb][2][nt][1][cj+1][bc];
      float xq0 = p_s[pb][3][nt][0][cj][bc]   + p_s[pb][3][nt][1][cj][bc];
      float xq1 = p_s[pb][3][nt][0][cj+1][bc] + p_s[pb][3][nt][1][cj+1][bc];
      float r0 = 1.f / (1.f + __expf(-(rp0 + era  + br0)));
      float r1 = 1.f / (1.f + __expf(-(rp1 + era1 + br1)));
      float z0 = 1.f / (1.f + __expf(-(zp0 + eza  + bz0)));
      float z1 = 1.f / (1.f + __expf(-(zp1 + eza1 + bz1)));
      float nx0 = (l > 0) ? (xq0 + bx0) : ena;
      float nx1 = (l > 0) ? (xq1 + bx1) : ena1;
      float e0 = __expf(2.f * (nx0 + r0 * (hp0 + bn0)));
      float e1 = __expf(2.f * (nx1 + r1 * (hp1 + bn1)));
      float n0 = (e0 - 1.f) / (e0 + 1.f);
      float n1 = (e1 - 1.f) / (e1 + 1.f);
      float h0 = (1.f - z0) * n0 + z0 * hres0; hres0 = h0;
      float h1 = (1.f - z1) * n1 + z1 * hres1; hres1 = h1;
      unsigned int pk = (unsigned int)f2bf(h0) | ((unsigned int)f2bf(h1) << 16);

      // h ring: data -> slot t+1; sentinel re-arm -> slot t+4
      st_coh_u32(hTl + (((size_t)((t + 1) & HRING_-1) * 32 + cb) << 9) + jg, pk);
      st_coh_u32(hTl + (((size_t)((t + 4) & HRING_-1) * 32 + cb) << 9) + jg, SENT32);

      if (l < 4){
        // x ring: data -> slot t; sentinel re-arm -> slot t+16
        st_coh_u32(xTw + (size_t)(t & XRING_-1) * XSLOT_ + (size_t)cb * 512 + jg, pk);
        st_coh_u32(xTw + (size_t)((t + 16) & XRING_-1) * XSLOT_ + (size_t)cb * 512 + jg, SENT32);
      } else {
        *(unsigned int*)&xout[((size_t)cb * T_ + t) * H_ + jg] = pk;
      }

      // consumer progress publish (reads-only semantics: no drain needed)
      if (l > 0 && (t & 3) == 3 && tid == 0) st_flag(&bp_pub[sub], t);

      // rotate xp prefetch regs
      era = erb; eza = ezb; ena = enb; era1 = erb1; eza1 = ezb1; ena1 = enb1;
      erb = erc; ezb = ezc; enb = enc; erb1 = erc1; ezb1 = ezc1; enb1 = enc1;
    }
  }
}

extern "C" void kernel_launch(void* const* d_in, const int* in_sizes, int n_in,
                              void* d_out, int out_size, void* d_ws, size_t ws_size,
                              hipStream_t stream){
  (void)in_sizes; (void)n_in; (void)out_size; (void)ws_size;
  const int*   note  = (const int*)d_in[0];
  const int*   chord = (const int*)d_in[1];
  const float* ctab  = (const float*)d_in[2];
  const float* ntab  = (const float*)d_in[3];
  const float* wih0  = (const float*)d_in[4];
  const float* whh0  = (const float*)d_in[5];
  const float* bih0  = (const float*)d_in[6];
  const float* bhh0  = (const float*)d_in[7];
  const float* wihr  = (const float*)d_in[8];
  const float* whhr  = (const float*)d_in[9];
  const float* bihr  = (const float*)d_in[10];
  const float* bhhr  = (const float*)d_in[11];
  const float* fcw   = (const float*)d_in[12];
  const float* fcb   = (const float*)d_in[13];
  float* out = (float*)d_out;

  char* ws = (char*)d_ws;
  size_t off = 0;
  auto alloc = [&](size_t bytes)->char*{
    char* p = ws + off; off = (off + bytes + 255) & ~(size_t)255; return p;
  };
  int*            cprog   = (int*)alloc(160 * sizeof(int));
  float*          xp      = (float*)alloc((size_t)BT_ * G3H_ * 4);
  unsigned short* wsw     = (unsigned short*)alloc((size_t)NBF_ * WSZ_ * 2);
  float*          bias_sw = (float*)alloc((size_t)NBF_ * 64 * 4);
  unsigned short* fcw_b   = (unsigned short*)alloc((size_t)CV_ * H_ * 2);
  unsigned short* xout    = (unsigned short*)alloc((size_t)BT_ * H_ * 2);
  // overlapped region: phase1 {x0, wih0_b} / phase2 {hT, xT}
  const size_t hT_bytes = (size_t)5 * HRING_ * 32 * 512 * 2;            // 2.62 MB
  const size_t hT_al    = (hT_bytes + 255) & ~(size_t)255;
  const size_t xT_bytes = (size_t)4 * XRING_ * XSLOT_ * 2;              // 4.19 MB
  const size_t p2_bytes = hT_al + xT_bytes;
  const size_t x0_bytes = (size_t)BT_ * K0_ * 2;                        // 33.55 MB
  const size_t x0_al    = (x0_bytes + 255) & ~(size_t)255;
  const size_t p1_bytes = x0_al + (size_t)G3H_ * K0_ * 2;               // 36.70 MB
  char* ovl = alloc(p1_bytes > p2_bytes ? p1_bytes : p2_bytes);
  unsigned short* x0     = (unsigned short*)ovl;
  unsigned short* wih0_b = (unsigned short*)(ovl + x0_al);
  unsigned short* hT     = (unsigned short*)ovl;
  unsigned short* xT     = (unsigned short*)(ovl + hT_al);

  hipMemsetAsync(cprog, 0, 160 * sizeof(int), stream);

  { int n = G3H_ * K0_; convert_bf16<<<(n + 255) / 256, 256, 0, stream>>>(wih0, wih0_b, n); }
  { int n = CV_ * H_;   convert_bf16<<<(n + 255) / 256, 256, 0, stream>>>(fcw, fcw_b, n); }
  { int n = NBF_ * WSZ_;
    prep_wfrag<<<(n + 255) / 256, 256, 0, stream>>>(whh0, whhr, wihr, wsw, n); }
  { int n = NBF_ * 64;
    prep_bias<<<(n + 255) / 256, 256, 0, stream>>>(bhh0, bihr, bhhr, bias_sw, n); }

  emb_kernel<<<BT_, 64, 0, stream>>>(note, chord, ctab, ntab, x0);

  // layer-0 input projection: xp = x0 @ wih0^T + bih0, layout [T][3H][B]
  gemm_bt<<<dim3(G3H_ / 64, BT_ / 64), 256, 0, stream>>>(
      x0, wih0_b, bih0, xp, BT_, G3H_, K0_, 1);

  // x0 / wih0_b now dead -> arm rings over the same bytes (stream-ordered)
  hipMemsetAsync(hT, 0x7F, hT_bytes, stream);
  for (int ll = 0; ll < 5; ++ll)   // slot 0 = h(0) = zeros
    hipMemsetAsync(hT + (size_t)ll * (HRING_ * 32 * 512), 0, 32 * 512 * 2, stream);
  hipMemsetAsync(xT, 0x7F, xT_bytes, stream);

  gru_fused<<<NBF_, 256, 0, stream>>>(xp, wsw, bias_sw, hT, xT, xout, cprog);

  // FC: out = xout @ fcw^T + fcb
  gemm_bt<<<dim3((CV_ + 63) / 64, BT_ / 64), 256, 0, stream>>>(
      xout, fcw_b, fcb, out, BT_, CV_, H_, 0);
}

// Round 6
// 5935.463 us; speedup vs baseline: 1.0839x; 1.0839x over previous
//
#include <hip/hip_runtime.h>
#include <hip/hip_bf16.h>

#define B_   32
#define T_   512
#define NN_  16
#define CV_  150
#define D_   512
#define H_   512
#define BT_  16384      // B*T
#define K0_  1024       // 2*D
#define G3H_ 1536       // 3*H
#define NBF_ 160        // 5 * 32
#define WSZ_ 49152      // bf16 elems of swizzled W per block (96 frags * 512)
#define XSLOT_ 16384    // elems per x ring slot (32*512)
#define XRING_ 32
#define HRING_ 8
#define SENT32 0x7f7f7f7fu
#define HCAP 16384
#define XCAP 16384
#define BCAP 65536

using bf16x8 = __attribute__((ext_vector_type(8))) short;
using f32x4  = __attribute__((ext_vector_type(4))) float;
using u32x4  = __attribute__((ext_vector_type(4))) unsigned int;
typedef unsigned long long u64;

__device__ __forceinline__ unsigned short f2bf(float f){
  unsigned int u = __builtin_bit_cast(unsigned int, f);
  u += 0x7fffu + ((u >> 16) & 1u);           // RNE
  return (unsigned short)(u >> 16);
}

__device__ __forceinline__ void store8(unsigned short* p, f32x4 a, f32x4 b){
  union { unsigned short us[8]; u32x4 v; } u;
  u.us[0]=f2bf(a[0]); u.us[1]=f2bf(a[1]); u.us[2]=f2bf(a[2]); u.us[3]=f2bf(a[3]);
  u.us[4]=f2bf(b[0]); u.us[5]=f2bf(b[1]); u.us[6]=f2bf(b[2]); u.us[7]=f2bf(b[3]);
  *(u32x4*)p = u.v;
}

// agent-scope (device-coherent) helpers: relaxed atomics, no fences (proven r0/r3)
__device__ __forceinline__ u64 ld_coh_u64(const u64* p){
  return __hip_atomic_load(p, __ATOMIC_RELAXED, __HIP_MEMORY_SCOPE_AGENT);
}
__device__ __forceinline__ void st_coh_u32(void* p, unsigned int v){
  __hip_atomic_store((unsigned int*)p, v, __ATOMIC_RELAXED, __HIP_MEMORY_SCOPE_AGENT);
}
__device__ __forceinline__ void st_flag(int* p, int v){
  __hip_atomic_store(p, v, __ATOMIC_RELAXED, __HIP_MEMORY_SCOPE_AGENT);
}
__device__ __forceinline__ int ld_flag(const int* p){
  return __hip_atomic_load(p, __ATOMIC_RELAXED, __HIP_MEMORY_SCOPE_AGENT);
}

__device__ __forceinline__ bool bad64(u64 q){
  return ((unsigned int)q == SENT32) | ((unsigned int)(q >> 32) == SENT32);
}

// ---------------- fp32 -> bf16 weight conversion ----------------
__global__ void convert_bf16(const float* __restrict__ src,
                             unsigned short* __restrict__ dst, int n){
  int i = blockIdx.x * 256 + threadIdx.x;
  if (i < n) dst[i] = f2bf(src[i]);
}

// ---------------- swizzle W into MFMA A-frag layout ----------------
__global__ void prep_wfrag(const float* __restrict__ whh0,
                           const float* __restrict__ whhr,
                           const float* __restrict__ wihr,
                           unsigned short* __restrict__ wsw, int total){
  int idx = blockIdx.x * 256 + threadIdx.x;
  if (idx >= total) return;
  int pos = idx & 511;
  int lam = pos >> 3, e = pos & 7;
  int fr  = idx >> 9;
  int ks  = fr & 31;
  int g   = (fr >> 5) % 3;
  int blk = fr / 96;
  int sub = blk & 31, l = blk >> 5;
  int row = g * 512 + sub * 16 + (lam & 15);
  int k   = (ks & 15) * 32 + (lam >> 4) * 8 + e;
  float v;
  if (l == 0) v = (ks < 16) ? whh0[(size_t)row * H_ + k] : 0.f;
  else {
    const float* w = (ks < 16) ? (whhr + (size_t)(l - 1) * G3H_ * H_)
                               : (wihr + (size_t)(l - 1) * G3H_ * H_);
    v = w[(size_t)row * H_ + k];
  }
  wsw[idx] = f2bf(v);
}

__global__ void prep_bias(const float* __restrict__ bhh0,
                          const float* __restrict__ bihr,
                          const float* __restrict__ bhhr,
                          float* __restrict__ bias_sw, int total){
  int idx = blockIdx.x * 256 + threadIdx.x;
  if (idx >= total) return;
  int q = idx & 3, u = (idx >> 2) & 15, sub = (idx >> 6) & 31, l = idx >> 11;
  int j = sub * 16 + u;
  float v;
  if (l == 0){
    v = (q == 0) ? bhh0[j] : (q == 1) ? bhh0[512 + j] : (q == 2) ? 0.f : bhh0[1024 + j];
  } else {
    const float* bi = bihr + (size_t)(l - 1) * G3H_;
    const float* bh = bhhr + (size_t)(l - 1) * G3H_;
    v = (q == 0) ? bi[j] + bh[j]
      : (q == 1) ? bi[512 + j] + bh[512 + j]
      : (q == 2) ? bi[1024 + j] : bh[1024 + j];
  }
  bias_sw[idx] = v;
}

// ---------------- embeddings ----------------
__global__ __launch_bounds__(64) void emb_kernel(
    const int* __restrict__ note, const int* __restrict__ chord,
    const float* __restrict__ ctab, const float* __restrict__ ntab,
    unsigned short* __restrict__ x0){
  const int bt = blockIdx.x;
  const int tid = threadIdx.x;
  __shared__ int sn[NN_];
  if (tid < NN_) sn[tid] = note[bt * NN_ + tid];
  __syncthreads();
  float alive = 1.f, cnt = 0.f;
  float msk[NN_];
  #pragma unroll
  for (int k = 0; k < NN_; ++k){ if (sn[k] == 0) alive = 0.f; msk[k] = alive; cnt += alive; }
  const float inv = 1.f / fmaxf(cnt, 1.f);
  const int ch = chord[bt];
  const int d0 = tid * 8;
  f32x4 c0 = {0.f,0.f,0.f,0.f}, c1 = {0.f,0.f,0.f,0.f};
  if (ch != 0){
    const float* cp = ctab + (size_t)ch * D_ + d0;
    c0 = *(const f32x4*)cp; c1 = *(const f32x4*)(cp + 4);
  }
  f32x4 s0 = {0.f,0.f,0.f,0.f}, s1 = {0.f,0.f,0.f,0.f};
  #pragma unroll
  for (int k = 0; k < NN_; ++k){
    if (msk[k] != 0.f){
      const float* np = ntab + (size_t)sn[k] * D_ + d0;
      s0 += *(const f32x4*)np;
      s1 += *(const f32x4*)(np + 4);
    }
  }
  s0 *= inv; s1 *= inv;
  unsigned short* o = x0 + (size_t)bt * K0_ + d0;
  store8(o, c0, c1);
  store8(o + D_, s0, s1);
}

// ---------------- bf16 MFMA GEMM:  Y = X[M,K] @ W[N,K]^T + bias ----------------
__global__ __launch_bounds__(256) void gemm_bt(
    const unsigned short* __restrict__ X, const unsigned short* __restrict__ W,
    const float* __restrict__ bias, float* __restrict__ Y,
    int M, int N, int K, int wmode){
  const int lane = threadIdx.x & 63;
  const int wave = threadIdx.x >> 6;
  const int l15 = lane & 15, kq4 = lane >> 4;
  const int m_frag = blockIdx.y * 64 + wave * 16 + l15;
  const int n_base = blockIdx.x * 64;
  f32x4 acc[4] = {{0.f,0.f,0.f,0.f},{0.f,0.f,0.f,0.f},{0.f,0.f,0.f,0.f},{0.f,0.f,0.f,0.f}};
  const unsigned short* xptr = X + (size_t)m_frag * K + kq4 * 8;
  const unsigned short* wptr[4];
  #pragma unroll
  for (int i = 0; i < 4; ++i){
    int n = n_base + i * 16 + l15;
    if (n >= N) n = N - 1;
    wptr[i] = W + (size_t)n * K + kq4 * 8;
  }
  for (int k0 = 0; k0 < K; k0 += 32){
    bf16x8 a = *(const bf16x8*)(xptr + k0);
    #pragma unroll
    for (int i = 0; i < 4; ++i){
      bf16x8 b = *(const bf16x8*)(wptr[i] + k0);
      acc[i] = __builtin_amdgcn_mfma_f32_16x16x32_bf16(a, b, acc[i], 0, 0, 0);
    }
  }
  const int mrow = blockIdx.y * 64 + wave * 16 + kq4 * 4;
  #pragma unroll
  for (int i = 0; i < 4; ++i){
    int n = n_base + i * 16 + l15;
    if (n < N){
      float bv = bias[n];
      #pragma unroll
      for (int r = 0; r < 4; ++r){
        int m = mrow + r;
        float v = acc[i][r] + bv;
        if (wmode == 0) Y[(size_t)m * N + n] = v;
        else            Y[((size_t)(m & (T_-1)) * N + n) * B_ + (m >> 9)] = v;
      }
    }
  }
}

// ---------------- fused 5-layer GRU: sentinel-gated L3 exchange ----------------
// EXACT r3 protocol (proven passing): 160 blocks (l=blk>>5, sub=blk&31).
// h ring hT[l][t&7][b][u]: data at slot t+1, sentinel re-arm at slot t+4.
// x ring xT[l][t&31][b][u]: data at slot t, re-arm at slot t+16; bp every 4 steps
// waits consumer >= t-4 (published every 4) -> consumer >= ~t-11 > t-16.
// r6 consumer-side changes ONLY (no protocol change):
//  - incremental poll-and-consume: per h-frag wait -> MFMA immediately (straggler
//    latency overlaps MFMA+LDS of arrived frags)
//  - x loads issued BEFORE the h phase (x is ~2-4 steps old, nearly always ready)
//  - s_sleep backoff after 2 failed rounds (cuts 160-block L3 poll storm)
//  - combine stores h-data first, sentinels last
union Ufrag { u64 q[2]; bf16x8 v; };

__global__ __launch_bounds__(256, 1) void gru_fused(
    const float* __restrict__ xp, const unsigned short* __restrict__ wsw,
    const float* __restrict__ bias_sw, unsigned short* hT,
    unsigned short* xT, unsigned short* xout, int* cprog){
  __shared__ unsigned short w_s[96 * 512];     // 96 KB A-frags
  __shared__ float p_s[2][4][2][2][16][16];    // [pb][r,z,hn,xn][myn][kh][u][b] 16KB

  const int tid = threadIdx.x;
  const int blk = blockIdx.x;
  const int l   = blk >> 5;
  const int sub = blk & 31;

  { // W -> LDS
    const u32x4* src = (const u32x4*)(wsw + (size_t)blk * WSZ_);
    u32x4* dst = (u32x4*)w_s;
    #pragma unroll
    for (int i = 0; i < 24; ++i) dst[tid + 256 * i] = src[tid + 256 * i];
  }
  __syncthreads();

  const int lane = tid & 63, wave = tid >> 6;
  const int l15 = lane & 15, l4 = lane >> 4;
  const int myn = wave >> 1;            // batch 16-group
  const int kh  = wave & 1;             // K-half
  const int myb = (myn << 4) + l15;
  const int fro = (l4 << 3);
  const int khofs = kh * 256;           // element offset of the K-half
  const int khb = kh * 8;               // frag base of the K-half

  const int cb = tid & 31;
  const int cj = (tid >> 5) * 2;
  const int jg = sub * 16 + cj;
  const float* bsp = bias_sw + blk * 64;
  const float br0 = bsp[cj*4+0],     bz0 = bsp[cj*4+1],     bx0 = bsp[cj*4+2],     bn0 = bsp[cj*4+3];
  const float br1 = bsp[(cj+1)*4+0], bz1 = bsp[(cj+1)*4+1], bx1 = bsp[(cj+1)*4+2], bn1 = bsp[(cj+1)*4+3];
  float hres0 = 0.f, hres1 = 0.f;

  unsigned short* hTl = hT + (size_t)l * (HRING_ * 32 * 512);
  unsigned short* xTw = xT + (size_t)(l < 4 ? l : 0) * ((size_t)XRING_ * XSLOT_);
  const unsigned short* xTr = xT + (size_t)(l > 0 ? l - 1 : 0) * ((size_t)XRING_ * XSLOT_);
  const int* bp_own = cprog + (l << 5);          // consumers of my x publish here
  int*       bp_pub = cprog + ((l > 0 ? l - 1 : 0) << 5);

  // xp 2-ahead prefetch registers (layer 0 only)
  float era=0,eza=0,ena=0,era1=0,eza1=0,ena1=0;
  float erb=0,ezb=0,enb=0,erb1=0,ezb1=0,enb1=0;
  if (l == 0){
    { const float* xq = xp + (size_t)0 * (G3H_ * B_) + cb;
      era=xq[(size_t)(0*H_+jg)*B_]; era1=xq[(size_t)(0*H_+jg+1)*B_];
      eza=xq[(size_t)(1*H_+jg)*B_]; eza1=xq[(size_t)(1*H_+jg+1)*B_];
      ena=xq[(size_t)(2*H_+jg)*B_]; ena1=xq[(size_t)(2*H_+jg+1)*B_]; }
    { const float* xq = xp + (size_t)1 * (G3H_ * B_) + cb;
      erb=xq[(size_t)(0*H_+jg)*B_]; erb1=xq[(size_t)(0*H_+jg+1)*B_];
      ezb=xq[(size_t)(1*H_+jg)*B_]; ezb1=xq[(size_t)(1*H_+jg+1)*B_];
      enb=xq[(size_t)(2*H_+jg)*B_]; enb1=xq[(size_t)(2*H_+jg+1)*B_]; }
  }

  for (int t = 0; t < T_; ++t){
    const int pb = t & 1;

    // ---- issue x(t) loads FIRST (produced steps ago; hides under h phase) ----
    Ufrag xb[8];
    const unsigned short* xs = nullptr;
    if (l > 0){
      xs = xTr + (size_t)(t & (XRING_-1)) * XSLOT_ + (size_t)myb * 512 + khofs + fro;
      #pragma unroll
      for (int j = 0; j < 8; ++j){
        const u64* sp = (const u64*)(xs + (j << 5));
        xb[j].q[0] = ld_coh_u64(sp); xb[j].q[1] = ld_coh_u64(sp + 1);
      }
    }

    // ---- issue all h(t) frag loads ----
    Ufrag hb[8];
    const unsigned short* hf = hTl + (((size_t)(t & (HRING_-1)) * 32 + myb) << 9) + khofs + fro;
    #pragma unroll
    for (int j = 0; j < 8; ++j){
      const u64* sp = (const u64*)(hf + (j << 5));
      hb[j].q[0] = ld_coh_u64(sp); hb[j].q[1] = ld_coh_u64(sp + 1);
    }

    // ---- producer back-pressure (every 4 steps; r3-proven; overlaps h flight) ----
    if (l < 4 && t && (t & 3) == 0){
      int itc = 0;
      while (true){
        int v = (lane < 32) ? ld_flag(&bp_own[lane]) : 0x7fffffff;
        if (__all(v >= t - 4)) break;
        if (++itc > BCAP) break;
        __builtin_amdgcn_s_sleep(2);
      }
    }

    // ---- h phase: incremental poll-and-consume (wait frag j -> 3 MFMAs) ----
    f32x4 accR = {0.f,0.f,0.f,0.f}, accZ = {0.f,0.f,0.f,0.f};
    f32x4 accN = {0.f,0.f,0.f,0.f}, accX = {0.f,0.f,0.f,0.f};
    #pragma unroll
    for (int j = 0; j < 8; ++j){
      int itc = 0;
      while (__any((int)(bad64(hb[j].q[0]) | bad64(hb[j].q[1])))){
        if (++itc > HCAP) break;
        if (itc > 2) __builtin_amdgcn_s_sleep(2);
        const u64* sp = (const u64*)(hf + (j << 5));
        hb[j].q[0] = ld_coh_u64(sp); hb[j].q[1] = ld_coh_u64(sp + 1);
      }
      bf16x8 b  = hb[j].v;
      bf16x8 a0 = *(const bf16x8*)&w_s[(0 * 32 + khb + j) * 512 + lane * 8];
      bf16x8 a1 = *(const bf16x8*)&w_s[(1 * 32 + khb + j) * 512 + lane * 8];
      bf16x8 a2 = *(const bf16x8*)&w_s[(2 * 32 + khb + j) * 512 + lane * 8];
      accR = __builtin_amdgcn_mfma_f32_16x16x32_bf16(a0, b, accR, 0, 0, 0);
      accZ = __builtin_amdgcn_mfma_f32_16x16x32_bf16(a1, b, accZ, 0, 0, 0);
      accN = __builtin_amdgcn_mfma_f32_16x16x32_bf16(a2, b, accN, 0, 0, 0);
    }

    // ---- x phase: per-frag wait (nearly always ready) + MFMA ----
    if (l > 0){
      #pragma unroll
      for (int j = 0; j < 8; ++j){
        int itc = 0;
        while (__any((int)(bad64(xb[j].q[0]) | bad64(xb[j].q[1])))){
          if (++itc > XCAP) break;
          if (itc > 2) __builtin_amdgcn_s_sleep(2);
          const u64* sp = (const u64*)(xs + (j << 5));
          xb[j].q[0] = ld_coh_u64(sp); xb[j].q[1] = ld_coh_u64(sp + 1);
        }
        bf16x8 b  = xb[j].v;
        bf16x8 a0 = *(const bf16x8*)&w_s[(0 * 32 + 16 + khb + j) * 512 + lane * 8];
        bf16x8 a1 = *(const bf16x8*)&w_s[(1 * 32 + 16 + khb + j) * 512 + lane * 8];
        bf16x8 a2 = *(const bf16x8*)&w_s[(2 * 32 + 16 + khb + j) * 512 + lane * 8];
        accR = __builtin_amdgcn_mfma_f32_16x16x32_bf16(a0, b, accR, 0, 0, 0);
        accZ = __builtin_amdgcn_mfma_f32_16x16x32_bf16(a1, b, accZ, 0, 0, 0);
        accX = __builtin_amdgcn_mfma_f32_16x16x32_bf16(a2, b, accX, 0, 0, 0);  // xn
      }
    }

    // ---- xp prefetch for t+2 (layer 0) ----
    float erc=0,ezc=0,enc=0,erc1=0,ezc1=0,enc1=0;
    if (l == 0){
      const float* xq = xp + (size_t)((t + 2) & (T_ - 1)) * (G3H_ * B_) + cb;
      erc=xq[(size_t)(0*H_+jg)*B_]; erc1=xq[(size_t)(0*H_+jg+1)*B_];
      ezc=xq[(size_t)(1*H_+jg)*B_]; ezc1=xq[(size_t)(1*H_+jg+1)*B_];
      enc=xq[(size_t)(2*H_+jg)*B_]; enc1=xq[(size_t)(2*H_+jg+1)*B_];
    }

    // ---- partials -> p_s[pb] ----
    #pragma unroll
    for (int r = 0; r < 4; ++r){
      int u = l4 * 4 + r;
      p_s[pb][0][myn][kh][u][l15] = accR[r];
      p_s[pb][1][myn][kh][u][l15] = accZ[r];
      p_s[pb][2][myn][kh][u][l15] = accN[r];
      p_s[pb][3][myn][kh][u][l15] = accX[r];
    }
    __syncthreads();

    // ---- combine ----
    {
      const int nt = cb >> 4, bc = cb & 15;
      float rp0 = p_s[pb][0][nt][0][cj][bc]   + p_s[pb][0][nt][1][cj][bc];
      float rp1 = p_s[pb][0][nt][0][cj+1][bc] + p_s[pb][0][nt][1][cj+1][bc];
      float zp0 = p_s[pb][1][nt][0][cj][bc]   + p_s[pb][1][nt][1][cj][bc];
      float zp1 = p_s[pb][1][nt][0][cj+1][bc] + p_s[pb][1][nt][1][cj+1][bc];
      float hp0 = p_s[pb][2][nt][0][cj][bc]   + p_s[pb][2][nt][1][cj][bc];
      float hp1 = p_s[pb][2][nt][0][cj+1][bc] + p_s[pb][2][nt][1][cj+1][bc];
      float xq0 = p_s[pb][3][nt][0][cj][bc]   + p_s[pb][3][nt][1][cj][bc];
      float xq1 = p_s[pb][3][nt][0][cj+1][bc] + p_s[pb][3][nt][1][cj+1][bc];
      float r0 = 1.f / (1.f + __expf(-(rp0 + era  + br0)));
      float r1 = 1.f / (1.f + __expf(-(rp1 + era1 + br1)));
      float z0 = 1.f / (1.f + __expf(-(zp0 + eza  + bz0)));
      float z1 = 1.f / (1.f + __expf(-(zp1 + eza1 + bz1)));
      float nx0 = (l > 0) ? (xq0 + bx0) : ena;
      float nx1 = (l > 0) ? (xq1 + bx1) : ena1;
      float e0 = __expf(2.f * (nx0 + r0 * (hp0 + bn0)));
      float e1 = __expf(2.f * (nx1 + r1 * (hp1 + bn1)));
      float n0 = (e0 - 1.f) / (e0 + 1.f);
      float n1 = (e1 - 1.f) / (e1 + 1.f);
      float h0 = (1.f - z0) * n0 + z0 * hres0; hres0 = h0;
      float h1 = (1.f - z1) * n1 + z1 * hres1; hres1 = h1;
      unsigned int pk = (unsigned int)f2bf(h0) | ((unsigned int)f2bf(h1) << 16);

      // h data first (peers are waiting on it), then x data, then sentinels
      st_coh_u32(hTl + (((size_t)((t + 1) & (HRING_-1)) * 32 + cb) << 9) + jg, pk);
      if (l < 4)
        st_coh_u32(xTw + (size_t)(t & (XRING_-1)) * XSLOT_ + (size_t)cb * 512 + jg, pk);
      else
        *(unsigned int*)&xout[((size_t)cb * T_ + t) * H_ + jg] = pk;
      st_coh_u32(hTl + (((size_t)((t + 4) & (HRING_-1)) * 32 + cb) << 9) + jg, SENT32);
      if (l < 4)
        st_coh_u32(xTw + (size_t)((t + 16) & (XRING_-1)) * XSLOT_ + (size_t)cb * 512 + jg, SENT32);

      // consumer progress publish (every 4 steps; r3-proven)
      if (l > 0 && (t & 3) == 3 && tid == 0) st_flag(&bp_pub[sub], t);

      // rotate xp prefetch regs
      era = erb; eza = ezb; ena = enb; era1 = erb1; eza1 = ezb1; ena1 = enb1;
      erb = erc; ezb = ezc; enb = enc; erb1 = erc1; ezb1 = ezc1; enb1 = enc1;
    }
  }
}

extern "C" void kernel_launch(void* const* d_in, const int* in_sizes, int n_in,
                              void* d_out, int out_size, void* d_ws, size_t ws_size,
                              hipStream_t stream){
  (void)in_sizes; (void)n_in; (void)out_size; (void)ws_size;
  const int*   note  = (const int*)d_in[0];
  const int*   chord = (const int*)d_in[1];
  const float* ctab  = (const float*)d_in[2];
  const float* ntab  = (const float*)d_in[3];
  const float* wih0  = (const float*)d_in[4];
  const float* whh0  = (const float*)d_in[5];
  const float* bih0  = (const float*)d_in[6];
  const float* bhh0  = (const float*)d_in[7];
  const float* wihr  = (const float*)d_in[8];
  const float* whhr  = (const float*)d_in[9];
  const float* bihr  = (const float*)d_in[10];
  const float* bhhr  = (const float*)d_in[11];
  const float* fcw   = (const float*)d_in[12];
  const float* fcb   = (const float*)d_in[13];
  float* out = (float*)d_out;

  char* ws = (char*)d_ws;
  size_t off = 0;
  auto alloc = [&](size_t bytes)->char*{
    char* p = ws + off; off = (off + bytes + 255) & ~(size_t)255; return p;
  };
  int*            cprog   = (int*)alloc(160 * sizeof(int));
  float*          xp      = (float*)alloc((size_t)BT_ * G3H_ * 4);
  unsigned short* wsw     = (unsigned short*)alloc((size_t)NBF_ * WSZ_ * 2);
  float*          bias_sw = (float*)alloc((size_t)NBF_ * 64 * 4);
  unsigned short* fcw_b   = (unsigned short*)alloc((size_t)CV_ * H_ * 2);
  unsigned short* xout    = (unsigned short*)alloc((size_t)BT_ * H_ * 2);
  // overlapped region: phase1 {x0, wih0_b} / phase2 {hT, xT}
  const size_t hT_bytes = (size_t)5 * HRING_ * 32 * 512 * 2;            // 2.62 MB
  const size_t hT_al    = (hT_bytes + 255) & ~(size_t)255;
  const size_t xT_bytes = (size_t)4 * XRING_ * XSLOT_ * 2;              // 4.19 MB
  const size_t p2_bytes = hT_al + xT_bytes;
  const size_t x0_bytes = (size_t)BT_ * K0_ * 2;                        // 33.55 MB
  const size_t x0_al    = (x0_bytes + 255) & ~(size_t)255;
  const size_t p1_bytes = x0_al + (size_t)G3H_ * K0_ * 2;               // 36.70 MB
  char* ovl = alloc(p1_bytes > p2_bytes ? p1_bytes : p2_bytes);
  unsigned short* x0     = (unsigned short*)ovl;
  unsigned short* wih0_b = (unsigned short*)(ovl + x0_al);
  unsigned short* hT     = (unsigned short*)ovl;
  unsigned short* xT     = (unsigned short*)(ovl + hT_al);

  hipMemsetAsync(cprog, 0, 160 * sizeof(int), stream);

  { int n = G3H_ * K0_; convert_bf16<<<(n + 255) / 256, 256, 0, stream>>>(wih0, wih0_b, n); }
  { int n = CV_ * H_;   convert_bf16<<<(n + 255) / 256, 256, 0, stream>>>(fcw, fcw_b, n); }
  { int n = NBF_ * WSZ_;
    prep_wfrag<<<(n + 255) / 256, 256, 0, stream>>>(whh0, whhr, wihr, wsw, n); }
  { int n = NBF_ * 64;
    prep_bias<<<(n + 255) / 256, 256, 0, stream>>>(bhh0, bihr, bhhr, bias_sw, n); }

  emb_kernel<<<BT_, 64, 0, stream>>>(note, chord, ctab, ntab, x0);

  // layer-0 input projection: xp = x0 @ wih0^T + bih0, layout [T][3H][B]
  gemm_bt<<<dim3(G3H_ / 64, BT_ / 64), 256, 0, stream>>>(
      x0, wih0_b, bih0, xp, BT_, G3H_, K0_, 1);

  // x0 / wih0_b now dead -> arm rings over the same bytes (stream-ordered)
  hipMemsetAsync(hT, 0x7F, hT_bytes, stream);
  for (int ll = 0; ll < 5; ++ll)   // slot 0 = h(0) = zeros
    hipMemsetAsync(hT + (size_t)ll * (HRING_ * 32 * 512), 0, 32 * 512 * 2, stream);
  hipMemsetAsync(xT, 0x7F, xT_bytes, stream);

  gru_fused<<<NBF_, 256, 0, stream>>>(xp, wsw, bias_sw, hT, xT, xout, cprog);

  // FC: out = xout @ fcw^T + fcb
  gemm_bt<<<dim3((CV_ + 63) / 64, BT_ / 64), 256, 0, stream>>>(
      xout, fcw_b, fcb, out, BT_, CV_, H_, 0);
}

// Round 7
// 5740.909 us; speedup vs baseline: 1.1206x; 1.0339x over previous
//
#include <hip/hip_runtime.h>
#include <hip/hip_bf16.h>

#define B_   32
#define T_   512
#define NN_  16
#define CV_  150
#define D_   512
#define H_   512
#define BT_  16384      // B*T
#define K0_  1024       // 2*D
#define G3H_ 1536       // 3*H
#define NBF_ 160        // 5 * 32
#define WSZ_ 49152      // bf16 elems of swizzled W per block (96 frags * 512)
#define XSLOT_ 16384    // elems per x ring slot (32*512)
#define XRING_ 32
#define HRING_ 8
#define SENT32 0x7f7f7f7fu
#define HCAP 16384
#define XCAP 16384
#define BCAP 65536

using bf16x8 = __attribute__((ext_vector_type(8))) short;
using f32x4  = __attribute__((ext_vector_type(4))) float;
using u32x4  = __attribute__((ext_vector_type(4))) unsigned int;
typedef unsigned long long u64;

__device__ __forceinline__ unsigned short f2bf(float f){
  unsigned int u = __builtin_bit_cast(unsigned int, f);
  u += 0x7fffu + ((u >> 16) & 1u);           // RNE
  return (unsigned short)(u >> 16);
}

__device__ __forceinline__ void store8(unsigned short* p, f32x4 a, f32x4 b){
  union { unsigned short us[8]; u32x4 v; } u;
  u.us[0]=f2bf(a[0]); u.us[1]=f2bf(a[1]); u.us[2]=f2bf(a[2]); u.us[3]=f2bf(a[3]);
  u.us[4]=f2bf(b[0]); u.us[5]=f2bf(b[1]); u.us[6]=f2bf(b[2]); u.us[7]=f2bf(b[3]);
  *(u32x4*)p = u.v;
}

// agent-scope (device-coherent) helpers: relaxed atomics, no fences (proven r0/r3/r6)
__device__ __forceinline__ u64 ld_coh_u64(const u64* p){
  return __hip_atomic_load(p, __ATOMIC_RELAXED, __HIP_MEMORY_SCOPE_AGENT);
}
__device__ __forceinline__ void st_coh_u32(void* p, unsigned int v){
  __hip_atomic_store((unsigned int*)p, v, __ATOMIC_RELAXED, __HIP_MEMORY_SCOPE_AGENT);
}
__device__ __forceinline__ void st_flag(int* p, int v){
  __hip_atomic_store(p, v, __ATOMIC_RELAXED, __HIP_MEMORY_SCOPE_AGENT);
}
__device__ __forceinline__ int ld_flag(const int* p){
  return __hip_atomic_load(p, __ATOMIC_RELAXED, __HIP_MEMORY_SCOPE_AGENT);
}

__device__ __forceinline__ bool bad64(u64 q){
  return ((unsigned int)q == SENT32) | ((unsigned int)(q >> 32) == SENT32);
}

// ---------------- fp32 -> bf16 weight conversion ----------------
__global__ void convert_bf16(const float* __restrict__ src,
                             unsigned short* __restrict__ dst, int n){
  int i = blockIdx.x * 256 + threadIdx.x;
  if (i < n) dst[i] = f2bf(src[i]);
}

// ---------------- swizzle W into MFMA A-frag layout ----------------
__global__ void prep_wfrag(const float* __restrict__ whh0,
                           const float* __restrict__ whhr,
                           const float* __restrict__ wihr,
                           unsigned short* __restrict__ wsw, int total){
  int idx = blockIdx.x * 256 + threadIdx.x;
  if (idx >= total) return;
  int pos = idx & 511;
  int lam = pos >> 3, e = pos & 7;
  int fr  = idx >> 9;
  int ks  = fr & 31;
  int g   = (fr >> 5) % 3;
  int blk = fr / 96;
  int sub = blk & 31, l = blk >> 5;
  int row = g * 512 + sub * 16 + (lam & 15);
  int k   = (ks & 15) * 32 + (lam >> 4) * 8 + e;
  float v;
  if (l == 0) v = (ks < 16) ? whh0[(size_t)row * H_ + k] : 0.f;
  else {
    const float* w = (ks < 16) ? (whhr + (size_t)(l - 1) * G3H_ * H_)
                               : (wihr + (size_t)(l - 1) * G3H_ * H_);
    v = w[(size_t)row * H_ + k];
  }
  wsw[idx] = f2bf(v);
}

__global__ void prep_bias(const float* __restrict__ bhh0,
                          const float* __restrict__ bihr,
                          const float* __restrict__ bhhr,
                          float* __restrict__ bias_sw, int total){
  int idx = blockIdx.x * 256 + threadIdx.x;
  if (idx >= total) return;
  int q = idx & 3, u = (idx >> 2) & 15, sub = (idx >> 6) & 31, l = idx >> 11;
  int j = sub * 16 + u;
  float v;
  if (l == 0){
    v = (q == 0) ? bhh0[j] : (q == 1) ? bhh0[512 + j] : (q == 2) ? 0.f : bhh0[1024 + j];
  } else {
    const float* bi = bihr + (size_t)(l - 1) * G3H_;
    const float* bh = bhhr + (size_t)(l - 1) * G3H_;
    v = (q == 0) ? bi[j] + bh[j]
      : (q == 1) ? bi[512 + j] + bh[512 + j]
      : (q == 2) ? bi[1024 + j] : bh[1024 + j];
  }
  bias_sw[idx] = v;
}

// ---------------- embeddings ----------------
__global__ __launch_bounds__(64) void emb_kernel(
    const int* __restrict__ note, const int* __restrict__ chord,
    const float* __restrict__ ctab, const float* __restrict__ ntab,
    unsigned short* __restrict__ x0){
  const int bt = blockIdx.x;
  const int tid = threadIdx.x;
  __shared__ int sn[NN_];
  if (tid < NN_) sn[tid] = note[bt * NN_ + tid];
  __syncthreads();
  float alive = 1.f, cnt = 0.f;
  float msk[NN_];
  #pragma unroll
  for (int k = 0; k < NN_; ++k){ if (sn[k] == 0) alive = 0.f; msk[k] = alive; cnt += alive; }
  const float inv = 1.f / fmaxf(cnt, 1.f);
  const int ch = chord[bt];
  const int d0 = tid * 8;
  f32x4 c0 = {0.f,0.f,0.f,0.f}, c1 = {0.f,0.f,0.f,0.f};
  if (ch != 0){
    const float* cp = ctab + (size_t)ch * D_ + d0;
    c0 = *(const f32x4*)cp; c1 = *(const f32x4*)(cp + 4);
  }
  f32x4 s0 = {0.f,0.f,0.f,0.f}, s1 = {0.f,0.f,0.f,0.f};
  #pragma unroll
  for (int k = 0; k < NN_; ++k){
    if (msk[k] != 0.f){
      const float* np = ntab + (size_t)sn[k] * D_ + d0;
      s0 += *(const f32x4*)np;
      s1 += *(const f32x4*)(np + 4);
    }
  }
  s0 *= inv; s1 *= inv;
  unsigned short* o = x0 + (size_t)bt * K0_ + d0;
  store8(o, c0, c1);
  store8(o + D_, s0, s1);
}

// ---------------- bf16 MFMA GEMM:  Y = X[M,K] @ W[N,K]^T + bias ----------------
__global__ __launch_bounds__(256) void gemm_bt(
    const unsigned short* __restrict__ X, const unsigned short* __restrict__ W,
    const float* __restrict__ bias, float* __restrict__ Y,
    int M, int N, int K, int wmode){
  const int lane = threadIdx.x & 63;
  const int wave = threadIdx.x >> 6;
  const int l15 = lane & 15, kq4 = lane >> 4;
  const int m_frag = blockIdx.y * 64 + wave * 16 + l15;
  const int n_base = blockIdx.x * 64;
  f32x4 acc[4] = {{0.f,0.f,0.f,0.f},{0.f,0.f,0.f,0.f},{0.f,0.f,0.f,0.f},{0.f,0.f,0.f,0.f}};
  const unsigned short* xptr = X + (size_t)m_frag * K + kq4 * 8;
  const unsigned short* wptr[4];
  #pragma unroll
  for (int i = 0; i < 4; ++i){
    int n = n_base + i * 16 + l15;
    if (n >= N) n = N - 1;
    wptr[i] = W + (size_t)n * K + kq4 * 8;
  }
  for (int k0 = 0; k0 < K; k0 += 32){
    bf16x8 a = *(const bf16x8*)(xptr + k0);
    #pragma unroll
    for (int i = 0; i < 4; ++i){
      bf16x8 b = *(const bf16x8*)(wptr[i] + k0);
      acc[i] = __builtin_amdgcn_mfma_f32_16x16x32_bf16(a, b, acc[i], 0, 0, 0);
    }
  }
  const int mrow = blockIdx.y * 64 + wave * 16 + kq4 * 4;
  #pragma unroll
  for (int i = 0; i < 4; ++i){
    int n = n_base + i * 16 + l15;
    if (n < N){
      float bv = bias[n];
      #pragma unroll
      for (int r = 0; r < 4; ++r){
        int m = mrow + r;
        float v = acc[i][r] + bv;
        if (wmode == 0) Y[(size_t)m * N + n] = v;
        else            Y[((size_t)(m & (T_-1)) * N + n) * B_ + (m >> 9)] = v;
      }
    }
  }
}

// ---------------- fused 5-layer GRU: sentinel-gated L3 exchange ----------------
// EXACT r3/r6 protocol (proven passing): 160 blocks (l=blk>>5, sub=blk&31).
// h ring hT[l][t&7][b][u]: data at slot t+1, sentinel re-arm at slot t+4.
// x ring xT[l][t&31][b][u]: data at slot t, re-arm at slot t+16; bp every 4 steps
// waits consumer >= t-4 (published every 4) -> consumer >= ~t-7 > t-16.
// r7 change (l>0 only): consume the x chain BEFORE the h chain. x(t) was produced
// >=1 pipeline-skew steps ago (always ready); its 24 MFMAs execute inside the
// h-store visibility window, so the h poll starts ~1us later and finds data.
// Same 32-term accumulation per acc (f32 reassociation only, ulp-level).
union Ufrag { u64 q[2]; bf16x8 v; };

__global__ __launch_bounds__(256, 1) void gru_fused(
    const float* __restrict__ xp, const unsigned short* __restrict__ wsw,
    const float* __restrict__ bias_sw, unsigned short* hT,
    unsigned short* xT, unsigned short* xout, int* cprog){
  __shared__ unsigned short w_s[96 * 512];     // 96 KB A-frags
  __shared__ float p_s[2][4][2][2][16][16];    // [pb][r,z,hn,xn][myn][kh][u][b] 16KB

  const int tid = threadIdx.x;
  const int blk = blockIdx.x;
  const int l   = blk >> 5;
  const int sub = blk & 31;

  { // W -> LDS
    const u32x4* src = (const u32x4*)(wsw + (size_t)blk * WSZ_);
    u32x4* dst = (u32x4*)w_s;
    #pragma unroll
    for (int i = 0; i < 24; ++i) dst[tid + 256 * i] = src[tid + 256 * i];
  }
  __syncthreads();

  const int lane = tid & 63, wave = tid >> 6;
  const int l15 = lane & 15, l4 = lane >> 4;
  const int myn = wave >> 1;            // batch 16-group
  const int kh  = wave & 1;             // K-half
  const int myb = (myn << 4) + l15;
  const int fro = (l4 << 3);
  const int khofs = kh * 256;           // element offset of the K-half
  const int khb = kh * 8;               // frag base of the K-half

  const int cb = tid & 31;
  const int cj = (tid >> 5) * 2;
  const int jg = sub * 16 + cj;
  const float* bsp = bias_sw + blk * 64;
  const float br0 = bsp[cj*4+0],     bz0 = bsp[cj*4+1],     bx0 = bsp[cj*4+2],     bn0 = bsp[cj*4+3];
  const float br1 = bsp[(cj+1)*4+0], bz1 = bsp[(cj+1)*4+1], bx1 = bsp[(cj+1)*4+2], bn1 = bsp[(cj+1)*4+3];
  float hres0 = 0.f, hres1 = 0.f;

  unsigned short* hTl = hT + (size_t)l * (HRING_ * 32 * 512);
  unsigned short* xTw = xT + (size_t)(l < 4 ? l : 0) * ((size_t)XRING_ * XSLOT_);
  const unsigned short* xTr = xT + (size_t)(l > 0 ? l - 1 : 0) * ((size_t)XRING_ * XSLOT_);
  const int* bp_own = cprog + (l << 5);          // consumers of my x publish here
  int*       bp_pub = cprog + ((l > 0 ? l - 1 : 0) << 5);

  // xp 2-ahead prefetch registers (layer 0 only)
  float era=0,eza=0,ena=0,era1=0,eza1=0,ena1=0;
  float erb=0,ezb=0,enb=0,erb1=0,ezb1=0,enb1=0;
  if (l == 0){
    { const float* xq = xp + (size_t)0 * (G3H_ * B_) + cb;
      era=xq[(size_t)(0*H_+jg)*B_]; era1=xq[(size_t)(0*H_+jg+1)*B_];
      eza=xq[(size_t)(1*H_+jg)*B_]; eza1=xq[(size_t)(1*H_+jg+1)*B_];
      ena=xq[(size_t)(2*H_+jg)*B_]; ena1=xq[(size_t)(2*H_+jg+1)*B_]; }
    { const float* xq = xp + (size_t)1 * (G3H_ * B_) + cb;
      erb=xq[(size_t)(0*H_+jg)*B_]; erb1=xq[(size_t)(0*H_+jg+1)*B_];
      ezb=xq[(size_t)(1*H_+jg)*B_]; ezb1=xq[(size_t)(1*H_+jg+1)*B_];
      enb=xq[(size_t)(2*H_+jg)*B_]; enb1=xq[(size_t)(2*H_+jg+1)*B_]; }
  }

  for (int t = 0; t < T_; ++t){
    const int pb = t & 1;

    // ---- issue x(t) loads (produced >=1 skew-steps ago) ----
    Ufrag xb[8];
    const unsigned short* xs = nullptr;
    if (l > 0){
      xs = xTr + (size_t)(t & (XRING_-1)) * XSLOT_ + (size_t)myb * 512 + khofs + fro;
      #pragma unroll
      for (int j = 0; j < 8; ++j){
        const u64* sp = (const u64*)(xs + (j << 5));
        xb[j].q[0] = ld_coh_u64(sp); xb[j].q[1] = ld_coh_u64(sp + 1);
      }
    }

    // ---- issue all h(t) frag loads (early miss -> cheap; real poll is later) ----
    Ufrag hb[8];
    const unsigned short* hf = hTl + (((size_t)(t & (HRING_-1)) * 32 + myb) << 9) + khofs + fro;
    #pragma unroll
    for (int j = 0; j < 8; ++j){
      const u64* sp = (const u64*)(hf + (j << 5));
      hb[j].q[0] = ld_coh_u64(sp); hb[j].q[1] = ld_coh_u64(sp + 1);
    }

    // ---- producer back-pressure (every 4 steps; proven margins) ----
    if (l < 4 && t && (t & 3) == 0){
      int itc = 0;
      while (true){
        int v = (lane < 32) ? ld_flag(&bp_own[lane]) : 0x7fffffff;
        if (__all(v >= t - 4)) break;
        if (++itc > BCAP) break;
        __builtin_amdgcn_s_sleep(2);
      }
    }

    f32x4 accR = {0.f,0.f,0.f,0.f}, accZ = {0.f,0.f,0.f,0.f};
    f32x4 accN = {0.f,0.f,0.f,0.f}, accX = {0.f,0.f,0.f,0.f};

    // ---- x phase FIRST: fills the h-store visibility window with real work ----
    if (l > 0){
      #pragma unroll
      for (int j = 0; j < 8; ++j){
        int itc = 0;
        while (__any((int)(bad64(xb[j].q[0]) | bad64(xb[j].q[1])))){
          if (++itc > XCAP) break;
          if (itc > 2) __builtin_amdgcn_s_sleep(2);
          const u64* sp = (const u64*)(xs + (j << 5));
          xb[j].q[0] = ld_coh_u64(sp); xb[j].q[1] = ld_coh_u64(sp + 1);
        }
        bf16x8 b  = xb[j].v;
        bf16x8 a0 = *(const bf16x8*)&w_s[(0 * 32 + 16 + khb + j) * 512 + lane * 8];
        bf16x8 a1 = *(const bf16x8*)&w_s[(1 * 32 + 16 + khb + j) * 512 + lane * 8];
        bf16x8 a2 = *(const bf16x8*)&w_s[(2 * 32 + 16 + khb + j) * 512 + lane * 8];
        accR = __builtin_amdgcn_mfma_f32_16x16x32_bf16(a0, b, accR, 0, 0, 0);
        accZ = __builtin_amdgcn_mfma_f32_16x16x32_bf16(a1, b, accZ, 0, 0, 0);
        accX = __builtin_amdgcn_mfma_f32_16x16x32_bf16(a2, b, accX, 0, 0, 0);  // xn
      }
    }

    // ---- h phase: incremental poll-and-consume (wait frag j -> 3 MFMAs) ----
    #pragma unroll
    for (int j = 0; j < 8; ++j){
      int itc = 0;
      while (__any((int)(bad64(hb[j].q[0]) | bad64(hb[j].q[1])))){
        if (++itc > HCAP) break;
        if (itc > 2) __builtin_amdgcn_s_sleep(2);
        const u64* sp = (const u64*)(hf + (j << 5));
        hb[j].q[0] = ld_coh_u64(sp); hb[j].q[1] = ld_coh_u64(sp + 1);
      }
      bf16x8 b  = hb[j].v;
      bf16x8 a0 = *(const bf16x8*)&w_s[(0 * 32 + khb + j) * 512 + lane * 8];
      bf16x8 a1 = *(const bf16x8*)&w_s[(1 * 32 + khb + j) * 512 + lane * 8];
      bf16x8 a2 = *(const bf16x8*)&w_s[(2 * 32 + khb + j) * 512 + lane * 8];
      accR = __builtin_amdgcn_mfma_f32_16x16x32_bf16(a0, b, accR, 0, 0, 0);
      accZ = __builtin_amdgcn_mfma_f32_16x16x32_bf16(a1, b, accZ, 0, 0, 0);
      accN = __builtin_amdgcn_mfma_f32_16x16x32_bf16(a2, b, accN, 0, 0, 0);
    }

    // ---- xp prefetch for t+2 (layer 0) ----
    float erc=0,ezc=0,enc=0,erc1=0,ezc1=0,enc1=0;
    if (l == 0){
      const float* xq = xp + (size_t)((t + 2) & (T_ - 1)) * (G3H_ * B_) + cb;
      erc=xq[(size_t)(0*H_+jg)*B_]; erc1=xq[(size_t)(0*H_+jg+1)*B_];
      ezc=xq[(size_t)(1*H_+jg)*B_]; ezc1=xq[(size_t)(1*H_+jg+1)*B_];
      enc=xq[(size_t)(2*H_+jg)*B_]; enc1=xq[(size_t)(2*H_+jg+1)*B_];
    }

    // ---- partials -> p_s[pb] ----
    #pragma unroll
    for (int r = 0; r < 4; ++r){
      int u = l4 * 4 + r;
      p_s[pb][0][myn][kh][u][l15] = accR[r];
      p_s[pb][1][myn][kh][u][l15] = accZ[r];
      p_s[pb][2][myn][kh][u][l15] = accN[r];
      p_s[pb][3][myn][kh][u][l15] = accX[r];
    }
    __syncthreads();

    // ---- combine ----
    {
      const int nt = cb >> 4, bc = cb & 15;
      float rp0 = p_s[pb][0][nt][0][cj][bc]   + p_s[pb][0][nt][1][cj][bc];
      float rp1 = p_s[pb][0][nt][0][cj+1][bc] + p_s[pb][0][nt][1][cj+1][bc];
      float zp0 = p_s[pb][1][nt][0][cj][bc]   + p_s[pb][1][nt][1][cj][bc];
      float zp1 = p_s[pb][1][nt][0][cj+1][bc] + p_s[pb][1][nt][1][cj+1][bc];
      float hp0 = p_s[pb][2][nt][0][cj][bc]   + p_s[pb][2][nt][1][cj][bc];
      float hp1 = p_s[pb][2][nt][0][cj+1][bc] + p_s[pb][2][nt][1][cj+1][bc];
      float xq0 = p_s[pb][3][nt][0][cj][bc]   + p_s[pb][3][nt][1][cj][bc];
      float xq1 = p_s[pb][3][nt][0][cj+1][bc] + p_s[pb][3][nt][1][cj+1][bc];
      float r0 = 1.f / (1.f + __expf(-(rp0 + era  + br0)));
      float r1 = 1.f / (1.f + __expf(-(rp1 + era1 + br1)));
      float z0 = 1.f / (1.f + __expf(-(zp0 + eza  + bz0)));
      float z1 = 1.f / (1.f + __expf(-(zp1 + eza1 + bz1)));
      float nx0 = (l > 0) ? (xq0 + bx0) : ena;
      float nx1 = (l > 0) ? (xq1 + bx1) : ena1;
      float e0 = __expf(2.f * (nx0 + r0 * (hp0 + bn0)));
      float e1 = __expf(2.f * (nx1 + r1 * (hp1 + bn1)));
      float n0 = (e0 - 1.f) / (e0 + 1.f);
      float n1 = (e1 - 1.f) / (e1 + 1.f);
      float h0 = (1.f - z0) * n0 + z0 * hres0; hres0 = h0;
      float h1 = (1.f - z1) * n1 + z1 * hres1; hres1 = h1;
      unsigned int pk = (unsigned int)f2bf(h0) | ((unsigned int)f2bf(h1) << 16);

      // h data first (peers are waiting on it), then x data, then sentinels
      st_coh_u32(hTl + (((size_t)((t + 1) & (HRING_-1)) * 32 + cb) << 9) + jg, pk);
      if (l < 4)
        st_coh_u32(xTw + (size_t)(t & (XRING_-1)) * XSLOT_ + (size_t)cb * 512 + jg, pk);
      else
        *(unsigned int*)&xout[((size_t)cb * T_ + t) * H_ + jg] = pk;
      st_coh_u32(hTl + (((size_t)((t + 4) & (HRING_-1)) * 32 + cb) << 9) + jg, SENT32);
      if (l < 4)
        st_coh_u32(xTw + (size_t)((t + 16) & (XRING_-1)) * XSLOT_ + (size_t)cb * 512 + jg, SENT32);

      // consumer progress publish (every 4 steps; proven)
      if (l > 0 && (t & 3) == 3 && tid == 0) st_flag(&bp_pub[sub], t);

      // rotate xp prefetch regs
      era = erb; eza = ezb; ena = enb; era1 = erb1; eza1 = ezb1; ena1 = enb1;
      erb = erc; ezb = ezc; enb = enc; erb1 = erc1; ezb1 = ezc1; enb1 = enc1;
    }
  }
}

extern "C" void kernel_launch(void* const* d_in, const int* in_sizes, int n_in,
                              void* d_out, int out_size, void* d_ws, size_t ws_size,
                              hipStream_t stream){
  (void)in_sizes; (void)n_in; (void)out_size; (void)ws_size;
  const int*   note  = (const int*)d_in[0];
  const int*   chord = (const int*)d_in[1];
  const float* ctab  = (const float*)d_in[2];
  const float* ntab  = (const float*)d_in[3];
  const float* wih0  = (const float*)d_in[4];
  const float* whh0  = (const float*)d_in[5];
  const float* bih0  = (const float*)d_in[6];
  const float* bhh0  = (const float*)d_in[7];
  const float* wihr  = (const float*)d_in[8];
  const float* whhr  = (const float*)d_in[9];
  const float* bihr  = (const float*)d_in[10];
  const float* bhhr  = (const float*)d_in[11];
  const float* fcw   = (const float*)d_in[12];
  const float* fcb   = (const float*)d_in[13];
  float* out = (float*)d_out;

  char* ws = (char*)d_ws;
  size_t off = 0;
  auto alloc = [&](size_t bytes)->char*{
    char* p = ws + off; off = (off + bytes + 255) & ~(size_t)255; return p;
  };
  int*            cprog   = (int*)alloc(160 * sizeof(int));
  float*          xp      = (float*)alloc((size_t)BT_ * G3H_ * 4);
  unsigned short* wsw     = (unsigned short*)alloc((size_t)NBF_ * WSZ_ * 2);
  float*          bias_sw = (float*)alloc((size_t)NBF_ * 64 * 4);
  unsigned short* fcw_b   = (unsigned short*)alloc((size_t)CV_ * H_ * 2);
  unsigned short* xout    = (unsigned short*)alloc((size_t)BT_ * H_ * 2);
  // overlapped region: phase1 {x0, wih0_b} / phase2 {hT, xT}
  const size_t hT_bytes = (size_t)5 * HRING_ * 32 * 512 * 2;            // 2.62 MB
  const size_t hT_al    = (hT_bytes + 255) & ~(size_t)255;
  const size_t xT_bytes = (size_t)4 * XRING_ * XSLOT_ * 2;              // 4.19 MB
  const size_t p2_bytes = hT_al + xT_bytes;
  const size_t x0_bytes = (size_t)BT_ * K0_ * 2;                        // 33.55 MB
  const size_t x0_al    = (x0_bytes + 255) & ~(size_t)255;
  const size_t p1_bytes = x0_al + (size_t)G3H_ * K0_ * 2;               // 36.70 MB
  char* ovl = alloc(p1_bytes > p2_bytes ? p1_bytes : p2_bytes);
  unsigned short* x0     = (unsigned short*)ovl;
  unsigned short* wih0_b = (unsigned short*)(ovl + x0_al);
  unsigned short* hT     = (unsigned short*)ovl;
  unsigned short* xT     = (unsigned short*)(ovl + hT_al);

  hipMemsetAsync(cprog, 0, 160 * sizeof(int), stream);

  { int n = G3H_ * K0_; convert_bf16<<<(n + 255) / 256, 256, 0, stream>>>(wih0, wih0_b, n); }
  { int n = CV_ * H_;   convert_bf16<<<(n + 255) / 256, 256, 0, stream>>>(fcw, fcw_b, n); }
  { int n = NBF_ * WSZ_;
    prep_wfrag<<<(n + 255) / 256, 256, 0, stream>>>(whh0, whhr, wihr, wsw, n); }
  { int n = NBF_ * 64;
    prep_bias<<<(n + 255) / 256, 256, 0, stream>>>(bhh0, bihr, bhhr, bias_sw, n); }

  emb_kernel<<<BT_, 64, 0, stream>>>(note, chord, ctab, ntab, x0);

  // layer-0 input projection: xp = x0 @ wih0^T + bih0, layout [T][3H][B]
  gemm_bt<<<dim3(G3H_ / 64, BT_ / 64), 256, 0, stream>>>(
      x0, wih0_b, bih0, xp, BT_, G3H_, K0_, 1);

  // x0 / wih0_b now dead -> arm rings over the same bytes (stream-ordered)
  hipMemsetAsync(hT, 0x7F, hT_bytes, stream);
  for (int ll = 0; ll < 5; ++ll)   // slot 0 = h(0) = zeros
    hipMemsetAsync(hT + (size_t)ll * (HRING_ * 32 * 512), 0, 32 * 512 * 2, stream);
  hipMemsetAsync(xT, 0x7F, xT_bytes, stream);

  gru_fused<<<NBF_, 256, 0, stream>>>(xp, wsw, bias_sw, hT, xT, xout, cprog);

  // FC: out = xout @ fcw^T + fcb
  gemm_bt<<<dim3((CV_ + 63) / 64, BT_ / 64), 256, 0, stream>>>(
      xout, fcw_b, fcb, out, BT_, CV_, H_, 0);
}

// Round 8
// 5318.253 us; speedup vs baseline: 1.2097x; 1.0795x over previous
//
#include <hip/hip_runtime.h>
#include <hip/hip_bf16.h>

#define B_   32
#define T_   512
#define NN_  16
#define CV_  150
#define D_   512
#define H_   512
#define BT_  16384      // B*T
#define K0_  1024       // 2*D
#define G3H_ 1536       // 3*H
#define NBF_ 160        // 5 * 32
#define GXB_ 6144       // 24 * 256 fused xp-GEMM blocks
#define WSZ_ 49152      // bf16 elems of swizzled W per block (96 frags * 512)
#define XSLOT_ 16384    // elems per x ring slot (32*512)
#define XRING_ 32
#define HRING_ 8
#define SENT32 0x7f7f7f7fu
#define HCAP 16384
#define XCAP 16384
#define BCAP 65536

using bf16x8 = __attribute__((ext_vector_type(8))) short;
using f32x4  = __attribute__((ext_vector_type(4))) float;
using u32x4  = __attribute__((ext_vector_type(4))) unsigned int;
typedef unsigned long long u64;

__device__ __forceinline__ unsigned short f2bf(float f){
  unsigned int u = __builtin_bit_cast(unsigned int, f);
  u += 0x7fffu + ((u >> 16) & 1u);           // RNE
  return (unsigned short)(u >> 16);
}

__device__ __forceinline__ void store8(unsigned short* p, f32x4 a, f32x4 b){
  union { unsigned short us[8]; u32x4 v; } u;
  u.us[0]=f2bf(a[0]); u.us[1]=f2bf(a[1]); u.us[2]=f2bf(a[2]); u.us[3]=f2bf(a[3]);
  u.us[4]=f2bf(b[0]); u.us[5]=f2bf(b[1]); u.us[6]=f2bf(b[2]); u.us[7]=f2bf(b[3]);
  *(u32x4*)p = u.v;
}

// agent-scope (device-coherent) helpers: relaxed atomics, no fences (proven r0/r3/r6/r7)
__device__ __forceinline__ u64 ld_coh_u64(const u64* p){
  return __hip_atomic_load(p, __ATOMIC_RELAXED, __HIP_MEMORY_SCOPE_AGENT);
}
__device__ __forceinline__ void st_coh_u32(void* p, unsigned int v){
  __hip_atomic_store((unsigned int*)p, v, __ATOMIC_RELAXED, __HIP_MEMORY_SCOPE_AGENT);
}
__device__ __forceinline__ float ld_coh_f32(const float* p){
  return __hip_atomic_load(p, __ATOMIC_RELAXED, __HIP_MEMORY_SCOPE_AGENT);
}
__device__ __forceinline__ void st_coh_f32(float* p, float v){
  __hip_atomic_store((unsigned int*)p, __builtin_bit_cast(unsigned int, v),
                     __ATOMIC_RELAXED, __HIP_MEMORY_SCOPE_AGENT);
}
__device__ __forceinline__ void st_flag(int* p, int v){
  __hip_atomic_store(p, v, __ATOMIC_RELAXED, __HIP_MEMORY_SCOPE_AGENT);
}
__device__ __forceinline__ int ld_flag(const int* p){
  return __hip_atomic_load(p, __ATOMIC_RELAXED, __HIP_MEMORY_SCOPE_AGENT);
}

__device__ __forceinline__ bool bad64(u64 q){
  return ((unsigned int)q == SENT32) | ((unsigned int)(q >> 32) == SENT32);
}

// ---------------- fp32 -> bf16 weight conversion ----------------
__global__ void convert_bf16(const float* __restrict__ src,
                             unsigned short* __restrict__ dst, int n){
  int i = blockIdx.x * 256 + threadIdx.x;
  if (i < n) dst[i] = f2bf(src[i]);
}

// ---------------- swizzle W into MFMA A-frag layout ----------------
__global__ void prep_wfrag(const float* __restrict__ whh0,
                           const float* __restrict__ whhr,
                           const float* __restrict__ wihr,
                           unsigned short* __restrict__ wsw, int total){
  int idx = blockIdx.x * 256 + threadIdx.x;
  if (idx >= total) return;
  int pos = idx & 511;
  int lam = pos >> 3, e = pos & 7;
  int fr  = idx >> 9;
  int ks  = fr & 31;
  int g   = (fr >> 5) % 3;
  int blk = fr / 96;
  int sub = blk & 31, l = blk >> 5;
  int row = g * 512 + sub * 16 + (lam & 15);
  int k   = (ks & 15) * 32 + (lam >> 4) * 8 + e;
  float v;
  if (l == 0) v = (ks < 16) ? whh0[(size_t)row * H_ + k] : 0.f;
  else {
    const float* w = (ks < 16) ? (whhr + (size_t)(l - 1) * G3H_ * H_)
                               : (wihr + (size_t)(l - 1) * G3H_ * H_);
    v = w[(size_t)row * H_ + k];
  }
  wsw[idx] = f2bf(v);
}

__global__ void prep_bias(const float* __restrict__ bhh0,
                          const float* __restrict__ bihr,
                          const float* __restrict__ bhhr,
                          float* __restrict__ bias_sw, int total){
  int idx = blockIdx.x * 256 + threadIdx.x;
  if (idx >= total) return;
  int q = idx & 3, u = (idx >> 2) & 15, sub = (idx >> 6) & 31, l = idx >> 11;
  int j = sub * 16 + u;
  float v;
  if (l == 0){
    v = (q == 0) ? bhh0[j] : (q == 1) ? bhh0[512 + j] : (q == 2) ? 0.f : bhh0[1024 + j];
  } else {
    const float* bi = bihr + (size_t)(l - 1) * G3H_;
    const float* bh = bhhr + (size_t)(l - 1) * G3H_;
    v = (q == 0) ? bi[j] + bh[j]
      : (q == 1) ? bi[512 + j] + bh[512 + j]
      : (q == 2) ? bi[1024 + j] : bh[1024 + j];
  }
  bias_sw[idx] = v;
}

// ---------------- embeddings ----------------
__global__ __launch_bounds__(64) void emb_kernel(
    const int* __restrict__ note, const int* __restrict__ chord,
    const float* __restrict__ ctab, const float* __restrict__ ntab,
    unsigned short* __restrict__ x0){
  const int bt = blockIdx.x;
  const int tid = threadIdx.x;
  __shared__ int sn[NN_];
  if (tid < NN_) sn[tid] = note[bt * NN_ + tid];
  __syncthreads();
  float alive = 1.f, cnt = 0.f;
  float msk[NN_];
  #pragma unroll
  for (int k = 0; k < NN_; ++k){ if (sn[k] == 0) alive = 0.f; msk[k] = alive; cnt += alive; }
  const float inv = 1.f / fmaxf(cnt, 1.f);
  const int ch = chord[bt];
  const int d0 = tid * 8;
  f32x4 c0 = {0.f,0.f,0.f,0.f}, c1 = {0.f,0.f,0.f,0.f};
  if (ch != 0){
    const float* cp = ctab + (size_t)ch * D_ + d0;
    c0 = *(const f32x4*)cp; c1 = *(const f32x4*)(cp + 4);
  }
  f32x4 s0 = {0.f,0.f,0.f,0.f}, s1 = {0.f,0.f,0.f,0.f};
  #pragma unroll
  for (int k = 0; k < NN_; ++k){
    if (msk[k] != 0.f){
      const float* np = ntab + (size_t)sn[k] * D_ + d0;
      s0 += *(const f32x4*)np;
      s1 += *(const f32x4*)(np + 4);
    }
  }
  s0 *= inv; s1 *= inv;
  unsigned short* o = x0 + (size_t)bt * K0_ + d0;
  store8(o, c0, c1);
  store8(o + D_, s0, s1);
}

// ---------------- bf16 MFMA GEMM:  Y = X[M,K] @ W[N,K]^T + bias ----------------
__global__ __launch_bounds__(256) void gemm_bt(
    const unsigned short* __restrict__ X, const unsigned short* __restrict__ W,
    const float* __restrict__ bias, float* __restrict__ Y,
    int M, int N, int K, int wmode){
  const int lane = threadIdx.x & 63;
  const int wave = threadIdx.x >> 6;
  const int l15 = lane & 15, kq4 = lane >> 4;
  const int m_frag = blockIdx.y * 64 + wave * 16 + l15;
  const int n_base = blockIdx.x * 64;
  f32x4 acc[4] = {{0.f,0.f,0.f,0.f},{0.f,0.f,0.f,0.f},{0.f,0.f,0.f,0.f},{0.f,0.f,0.f,0.f}};
  const unsigned short* xptr = X + (size_t)m_frag * K + kq4 * 8;
  const unsigned short* wptr[4];
  #pragma unroll
  for (int i = 0; i < 4; ++i){
    int n = n_base + i * 16 + l15;
    if (n >= N) n = N - 1;
    wptr[i] = W + (size_t)n * K + kq4 * 8;
  }
  for (int k0 = 0; k0 < K; k0 += 32){
    bf16x8 a = *(const bf16x8*)(xptr + k0);
    #pragma unroll
    for (int i = 0; i < 4; ++i){
      bf16x8 b = *(const bf16x8*)(wptr[i] + k0);
      acc[i] = __builtin_amdgcn_mfma_f32_16x16x32_bf16(a, b, acc[i], 0, 0, 0);
    }
  }
  const int mrow = blockIdx.y * 64 + wave * 16 + kq4 * 4;
  #pragma unroll
  for (int i = 0; i < 4; ++i){
    int n = n_base + i * 16 + l15;
    if (n < N){
      float bv = bias[n];
      #pragma unroll
      for (int r = 0; r < 4; ++r){
        int m = mrow + r;
        float v = acc[i][r] + bv;
        if (wmode == 0) Y[(size_t)m * N + n] = v;
        else            Y[((size_t)(m & (T_-1)) * N + n) * B_ + (m >> 9)] = v;
      }
    }
  }
}

// ---------------- fused 5-layer GRU + fused xp-GEMM ----------------
// Blocks [0,160): EXACT r7 GRU protocol (proven passing).
//   h ring hT[l][t&7][b][u]: data at slot t+1, sentinel re-arm at slot t+4.
//   x ring xT[l][t&31][b][u]: data at slot t, re-arm at slot t+16; bp every 4 steps.
//   Per-step order: x-phase first (fills h-store visibility window), then h-phase.
// Blocks [160,160+6144): xp-GEMM role, chunk-major dispatch (t-chunk tc = idx/24>>5... 
//   gyy=idx/24: b=gyy&31, tc=gyy>>5 -> all of tc=0 dispatches first). After stores:
//   vmcnt(0)+barrier -> atomicAdd(gprog[tc]). Chunk tc valid when gprog[tc]==768.
// Layer-0 GRU blocks gate on gprog before first touch of each 64-step xp chunk; all
// xp traffic is agent-scope (intra-kernel production). All spins capped.
union Ufrag { u64 q[2]; bf16x8 v; };

__global__ __launch_bounds__(256, 1) void gru_fused(
    float* xp, const unsigned short* __restrict__ wsw,
    const float* __restrict__ bias_sw, unsigned short* hT,
    unsigned short* xT, unsigned short* xout, int* cprog,
    const unsigned short* __restrict__ x0g,
    const unsigned short* __restrict__ wih0g,
    const float* __restrict__ bih0g, int* gprog){
  __shared__ unsigned short w_s[96 * 512];     // 96 KB A-frags
  __shared__ float p_s[2][4][2][2][16][16];    // [pb][r,z,hn,xn][myn][kh][u][b] 16KB

  const int tid = threadIdx.x;
  const int blk = blockIdx.x;

  // =========== xp-GEMM role ===========
  if (blk >= NBF_){
    const int idx = blk - NBF_;
    const int gx  = idx % 24;            // n tile
    const int gyy = idx / 24;            // [0,256)
    const int bb  = gyy & 31, tc = gyy >> 5;
    const int m0  = bb * 512 + tc * 64;
    const int lane = tid & 63, wave = tid >> 6;
    const int l15 = lane & 15, kq4 = lane >> 4;
    const int m_frag = m0 + wave * 16 + l15;
    const int n_base = gx * 64;
    f32x4 acc[4] = {{0.f,0.f,0.f,0.f},{0.f,0.f,0.f,0.f},{0.f,0.f,0.f,0.f},{0.f,0.f,0.f,0.f}};
    const unsigned short* xptr = x0g + (size_t)m_frag * K0_ + kq4 * 8;
    const unsigned short* wptr[4];
    #pragma unroll
    for (int i = 0; i < 4; ++i){
      int n = n_base + i * 16 + l15;
      wptr[i] = wih0g + (size_t)n * K0_ + kq4 * 8;
    }
    for (int k0 = 0; k0 < K0_; k0 += 32){
      bf16x8 a = *(const bf16x8*)(xptr + k0);
      #pragma unroll
      for (int i = 0; i < 4; ++i){
        bf16x8 b = *(const bf16x8*)(wptr[i] + k0);
        acc[i] = __builtin_amdgcn_mfma_f32_16x16x32_bf16(a, b, acc[i], 0, 0, 0);
      }
    }
    const int mrow = m0 + wave * 16 + kq4 * 4;
    #pragma unroll
    for (int i = 0; i < 4; ++i){
      int n = n_base + i * 16 + l15;
      float bv = bih0g[n];
      #pragma unroll
      for (int r = 0; r < 4; ++r){
        int m = mrow + r;
        float v = acc[i][r] + bv;
        st_coh_f32(&xp[((size_t)(m & (T_-1)) * G3H_ + n) * B_ + (m >> 9)], v);
      }
    }
    asm volatile("s_waitcnt vmcnt(0)" ::: "memory");
    __syncthreads();                       // all 256 threads' stores drained
    if (tid == 0) atomicAdd(&gprog[tc], 1);
    return;
  }

  // =========== GRU role (byte-identical protocol to r7) ===========
  const int l   = blk >> 5;
  const int sub = blk & 31;

  { // W -> LDS
    const u32x4* src = (const u32x4*)(wsw + (size_t)blk * WSZ_);
    u32x4* dst = (u32x4*)w_s;
    #pragma unroll
    for (int i = 0; i < 24; ++i) dst[tid + 256 * i] = src[tid + 256 * i];
  }
  __syncthreads();

  const int lane = tid & 63, wave = tid >> 6;
  const int l15 = lane & 15, l4 = lane >> 4;
  const int myn = wave >> 1;            // batch 16-group
  const int kh  = wave & 1;             // K-half
  const int myb = (myn << 4) + l15;
  const int fro = (l4 << 3);
  const int khofs = kh * 256;           // element offset of the K-half
  const int khb = kh * 8;               // frag base of the K-half

  const int cb = tid & 31;
  const int cj = (tid >> 5) * 2;
  const int jg = sub * 16 + cj;
  const float* bsp = bias_sw + blk * 64;
  const float br0 = bsp[cj*4+0],     bz0 = bsp[cj*4+1],     bx0 = bsp[cj*4+2],     bn0 = bsp[cj*4+3];
  const float br1 = bsp[(cj+1)*4+0], bz1 = bsp[(cj+1)*4+1], bx1 = bsp[(cj+1)*4+2], bn1 = bsp[(cj+1)*4+3];
  float hres0 = 0.f, hres1 = 0.f;

  unsigned short* hTl = hT + (size_t)l * (HRING_ * 32 * 512);
  unsigned short* xTw = xT + (size_t)(l < 4 ? l : 0) * ((size_t)XRING_ * XSLOT_);
  const unsigned short* xTr = xT + (size_t)(l > 0 ? l - 1 : 0) * ((size_t)XRING_ * XSLOT_);
  const int* bp_own = cprog + (l << 5);          // consumers of my x publish here
  int*       bp_pub = cprog + ((l > 0 ? l - 1 : 0) << 5);

  // xp 2-ahead prefetch registers (layer 0 only); chunk-0 gate first
  float era=0,eza=0,ena=0,era1=0,eza1=0,ena1=0;
  float erb=0,ezb=0,enb=0,erb1=0,ezb1=0,enb1=0;
  if (l == 0){
    if (tid == 0){
      int itc = 0;
      while (ld_flag(&gprog[0]) < 768){
        if (++itc > (1 << 24)) break;
        __builtin_amdgcn_s_sleep(8);
      }
    }
    __syncthreads();
    { const float* xq = xp + (size_t)0 * (G3H_ * B_) + cb;
      era=ld_coh_f32(&xq[(size_t)(0*H_+jg)*B_]); era1=ld_coh_f32(&xq[(size_t)(0*H_+jg+1)*B_]);
      eza=ld_coh_f32(&xq[(size_t)(1*H_+jg)*B_]); eza1=ld_coh_f32(&xq[(size_t)(1*H_+jg+1)*B_]);
      ena=ld_coh_f32(&xq[(size_t)(2*H_+jg)*B_]); ena1=ld_coh_f32(&xq[(size_t)(2*H_+jg+1)*B_]); }
    { const float* xq = xp + (size_t)1 * (G3H_ * B_) + cb;
      erb=ld_coh_f32(&xq[(size_t)(0*H_+jg)*B_]); erb1=ld_coh_f32(&xq[(size_t)(0*H_+jg+1)*B_]);
      ezb=ld_coh_f32(&xq[(size_t)(1*H_+jg)*B_]); ezb1=ld_coh_f32(&xq[(size_t)(1*H_+jg+1)*B_]);
      enb=ld_coh_f32(&xq[(size_t)(2*H_+jg)*B_]); enb1=ld_coh_f32(&xq[(size_t)(2*H_+jg+1)*B_]); }
  }

  for (int t = 0; t < T_; ++t){
    const int pb = t & 1;

    // ---- issue x(t) loads (produced >=1 skew-steps ago) ----
    Ufrag xb[8];
    const unsigned short* xs = nullptr;
    if (l > 0){
      xs = xTr + (size_t)(t & (XRING_-1)) * XSLOT_ + (size_t)myb * 512 + khofs + fro;
      #pragma unroll
      for (int j = 0; j < 8; ++j){
        const u64* sp = (const u64*)(xs + (j << 5));
        xb[j].q[0] = ld_coh_u64(sp); xb[j].q[1] = ld_coh_u64(sp + 1);
      }
    }

    // ---- issue all h(t) frag loads (early miss -> cheap; real poll is later) ----
    Ufrag hb[8];
    const unsigned short* hf = hTl + (((size_t)(t & (HRING_-1)) * 32 + myb) << 9) + khofs + fro;
    #pragma unroll
    for (int j = 0; j < 8; ++j){
      const u64* sp = (const u64*)(hf + (j << 5));
      hb[j].q[0] = ld_coh_u64(sp); hb[j].q[1] = ld_coh_u64(sp + 1);
    }

    // ---- producer back-pressure (every 4 steps; proven margins) ----
    if (l < 4 && l > 0 && t && (t & 3) == 0){
      int itc = 0;
      while (true){
        int v = (lane < 32) ? ld_flag(&bp_own[lane]) : 0x7fffffff;
        if (__all(v >= t - 4)) break;
        if (++itc > BCAP) break;
        __builtin_amdgcn_s_sleep(2);
      }
    } else if (l == 0 && t && (t & 3) == 0){
      int itc = 0;
      while (true){
        int v = (lane < 32) ? ld_flag(&bp_own[lane]) : 0x7fffffff;
        if (__all(v >= t - 4)) break;
        if (++itc > BCAP) break;
        __builtin_amdgcn_s_sleep(2);
      }
    }

    f32x4 accR = {0.f,0.f,0.f,0.f}, accZ = {0.f,0.f,0.f,0.f};
    f32x4 accN = {0.f,0.f,0.f,0.f}, accX = {0.f,0.f,0.f,0.f};

    // ---- x phase FIRST: fills the h-store visibility window with real work ----
    if (l > 0){
      #pragma unroll
      for (int j = 0; j < 8; ++j){
        int itc = 0;
        while (__any((int)(bad64(xb[j].q[0]) | bad64(xb[j].q[1])))){
          if (++itc > XCAP) break;
          if (itc > 2) __builtin_amdgcn_s_sleep(2);
          const u64* sp = (const u64*)(xs + (j << 5));
          xb[j].q[0] = ld_coh_u64(sp); xb[j].q[1] = ld_coh_u64(sp + 1);
        }
        bf16x8 b  = xb[j].v;
        bf16x8 a0 = *(const bf16x8*)&w_s[(0 * 32 + 16 + khb + j) * 512 + lane * 8];
        bf16x8 a1 = *(const bf16x8*)&w_s[(1 * 32 + 16 + khb + j) * 512 + lane * 8];
        bf16x8 a2 = *(const bf16x8*)&w_s[(2 * 32 + 16 + khb + j) * 512 + lane * 8];
        accR = __builtin_amdgcn_mfma_f32_16x16x32_bf16(a0, b, accR, 0, 0, 0);
        accZ = __builtin_amdgcn_mfma_f32_16x16x32_bf16(a1, b, accZ, 0, 0, 0);
        accX = __builtin_amdgcn_mfma_f32_16x16x32_bf16(a2, b, accX, 0, 0, 0);  // xn
      }
    }

    // ---- h phase: incremental poll-and-consume (wait frag j -> 3 MFMAs) ----
    #pragma unroll
    for (int j = 0; j < 8; ++j){
      int itc = 0;
      while (__any((int)(bad64(hb[j].q[0]) | bad64(hb[j].q[1])))){
        if (++itc > HCAP) break;
        if (itc > 2) __builtin_amdgcn_s_sleep(2);
        const u64* sp = (const u64*)(hf + (j << 5));
        hb[j].q[0] = ld_coh_u64(sp); hb[j].q[1] = ld_coh_u64(sp + 1);
      }
      bf16x8 b  = hb[j].v;
      bf16x8 a0 = *(const bf16x8*)&w_s[(0 * 32 + khb + j) * 512 + lane * 8];
      bf16x8 a1 = *(const bf16x8*)&w_s[(1 * 32 + khb + j) * 512 + lane * 8];
      bf16x8 a2 = *(const bf16x8*)&w_s[(2 * 32 + khb + j) * 512 + lane * 8];
      accR = __builtin_amdgcn_mfma_f32_16x16x32_bf16(a0, b, accR, 0, 0, 0);
      accZ = __builtin_amdgcn_mfma_f32_16x16x32_bf16(a1, b, accZ, 0, 0, 0);
      accN = __builtin_amdgcn_mfma_f32_16x16x32_bf16(a2, b, accN, 0, 0, 0);
    }

    // ---- xp chunk gate + prefetch for t+2 (layer 0) ----
    float erc=0,ezc=0,enc=0,erc1=0,ezc1=0,enc1=0;
    if (l == 0){
      if (((t + 2) & 63) == 0){
        const int ck = ((t + 2) & (T_ - 1)) >> 6;
        if (tid == 0){
          int itc = 0;
          while (ld_flag(&gprog[ck]) < 768){
            if (++itc > (1 << 24)) break;
            __builtin_amdgcn_s_sleep(8);
          }
        }
        __syncthreads();
      }
      const float* xq = xp + (size_t)((t + 2) & (T_ - 1)) * (G3H_ * B_) + cb;
      erc=ld_coh_f32(&xq[(size_t)(0*H_+jg)*B_]); erc1=ld_coh_f32(&xq[(size_t)(0*H_+jg+1)*B_]);
      ezc=ld_coh_f32(&xq[(size_t)(1*H_+jg)*B_]); ezc1=ld_coh_f32(&xq[(size_t)(1*H_+jg+1)*B_]);
      enc=ld_coh_f32(&xq[(size_t)(2*H_+jg)*B_]); enc1=ld_coh_f32(&xq[(size_t)(2*H_+jg+1)*B_]);
    }

    // ---- partials -> p_s[pb] ----
    #pragma unroll
    for (int r = 0; r < 4; ++r){
      int u = l4 * 4 + r;
      p_s[pb][0][myn][kh][u][l15] = accR[r];
      p_s[pb][1][myn][kh][u][l15] = accZ[r];
      p_s[pb][2][myn][kh][u][l15] = accN[r];
      p_s[pb][3][myn][kh][u][l15] = accX[r];
    }
    __syncthreads();

    // ---- combine ----
    {
      const int nt = cb >> 4, bc = cb & 15;
      float rp0 = p_s[pb][0][nt][0][cj][bc]   + p_s[pb][0][nt][1][cj][bc];
      float rp1 = p_s[pb][0][nt][0][cj+1][bc] + p_s[pb][0][nt][1][cj+1][bc];
      float zp0 = p_s[pb][1][nt][0][cj][bc]   + p_s[pb][1][nt][1][cj][bc];
      float zp1 = p_s[pb][1][nt][0][cj+1][bc] + p_s[pb][1][nt][1][cj+1][bc];
      float hp0 = p_s[pb][2][nt][0][cj][bc]   + p_s[pb][2][nt][1][cj][bc];
      float hp1 = p_s[pb][2][nt][0][cj+1][bc] + p_s[pb][2][nt][1][cj+1][bc];
      float xq0 = p_s[pb][3][nt][0][cj][bc]   + p_s[pb][3][nt][1][cj][bc];
      float xq1 = p_s[pb][3][nt][0][cj+1][bc] + p_s[pb][3][nt][1][cj+1][bc];
      float r0 = 1.f / (1.f + __expf(-(rp0 + era  + br0)));
      float r1 = 1.f / (1.f + __expf(-(rp1 + era1 + br1)));
      float z0 = 1.f / (1.f + __expf(-(zp0 + eza  + bz0)));
      float z1 = 1.f / (1.f + __expf(-(zp1 + eza1 + bz1)));
      float nx0 = (l > 0) ? (xq0 + bx0) : ena;
      float nx1 = (l > 0) ? (xq1 + bx1) : ena1;
      float e0 = __expf(2.f * (nx0 + r0 * (hp0 + bn0)));
      float e1 = __expf(2.f * (nx1 + r1 * (hp1 + bn1)));
      float n0 = (e0 - 1.f) / (e0 + 1.f);
      float n1 = (e1 - 1.f) / (e1 + 1.f);
      float h0 = (1.f - z0) * n0 + z0 * hres0; hres0 = h0;
      float h1 = (1.f - z1) * n1 + z1 * hres1; hres1 = h1;
      unsigned int pk = (unsigned int)f2bf(h0) | ((unsigned int)f2bf(h1) << 16);

      // h data first (peers are waiting on it), then x data, then sentinels
      st_coh_u32(hTl + (((size_t)((t + 1) & (HRING_-1)) * 32 + cb) << 9) + jg, pk);
      if (l < 4)
        st_coh_u32(xTw + (size_t)(t & (XRING_-1)) * XSLOT_ + (size_t)cb * 512 + jg, pk);
      else
        *(unsigned int*)&xout[((size_t)cb * T_ + t) * H_ + jg] = pk;
      st_coh_u32(hTl + (((size_t)((t + 4) & (HRING_-1)) * 32 + cb) << 9) + jg, SENT32);
      if (l < 4)
        st_coh_u32(xTw + (size_t)((t + 16) & (XRING_-1)) * XSLOT_ + (size_t)cb * 512 + jg, SENT32);

      // consumer progress publish (every 4 steps; proven)
      if (l > 0 && (t & 3) == 3 && tid == 0) st_flag(&bp_pub[sub], t);

      // rotate xp prefetch regs
      era = erb; eza = ezb; ena = enb; era1 = erb1; eza1 = ezb1; ena1 = enb1;
      erb = erc; ezb = ezc; enb = enc; erb1 = erc1; ezb1 = ezc1; enb1 = enc1;
    }
  }
}

extern "C" void kernel_launch(void* const* d_in, const int* in_sizes, int n_in,
                              void* d_out, int out_size, void* d_ws, size_t ws_size,
                              hipStream_t stream){
  (void)in_sizes; (void)n_in; (void)out_size; (void)ws_size;
  const int*   note  = (const int*)d_in[0];
  const int*   chord = (const int*)d_in[1];
  const float* ctab  = (const float*)d_in[2];
  const float* ntab  = (const float*)d_in[3];
  const float* wih0  = (const float*)d_in[4];
  const float* whh0  = (const float*)d_in[5];
  const float* bih0  = (const float*)d_in[6];
  const float* bhh0  = (const float*)d_in[7];
  const float* wihr  = (const float*)d_in[8];
  const float* whhr  = (const float*)d_in[9];
  const float* bihr  = (const float*)d_in[10];
  const float* bhhr  = (const float*)d_in[11];
  const float* fcw   = (const float*)d_in[12];
  const float* fcb   = (const float*)d_in[13];
  float* out = (float*)d_out;

  char* ws = (char*)d_ws;
  size_t off = 0;
  auto alloc = [&](size_t bytes)->char*{
    char* p = ws + off; off = (off + bytes + 255) & ~(size_t)255; return p;
  };
  int*            cprog   = (int*)alloc(160 * sizeof(int));
  int*            gprog   = (int*)alloc(8 * sizeof(int));
  float*          xp      = (float*)alloc((size_t)BT_ * G3H_ * 4);
  unsigned short* wsw     = (unsigned short*)alloc((size_t)NBF_ * WSZ_ * 2);
  float*          bias_sw = (float*)alloc((size_t)NBF_ * 64 * 4);
  unsigned short* fcw_b   = (unsigned short*)alloc((size_t)CV_ * H_ * 2);
  unsigned short* xout    = (unsigned short*)alloc((size_t)BT_ * H_ * 2);
  unsigned short* x0      = (unsigned short*)alloc((size_t)BT_ * K0_ * 2);
  unsigned short* wih0_b  = (unsigned short*)alloc((size_t)G3H_ * K0_ * 2);

  // h/x rings live in d_out scratch (9.83 MB >= 6.81 MB); FC fully overwrites out.
  const size_t hT_bytes = (size_t)5 * HRING_ * 32 * 512 * 2;            // 2.62 MB
  const size_t hT_al    = (hT_bytes + 255) & ~(size_t)255;
  const size_t xT_bytes = (size_t)4 * XRING_ * XSLOT_ * 2;              // 4.19 MB
  unsigned short* hT = (unsigned short*)d_out;
  unsigned short* xT = (unsigned short*)((char*)d_out + hT_al);

  hipMemsetAsync(cprog, 0, 160 * sizeof(int), stream);
  hipMemsetAsync(gprog, 0, 8 * sizeof(int), stream);
  hipMemsetAsync(hT, 0x7F, hT_bytes, stream);
  for (int ll = 0; ll < 5; ++ll)   // slot 0 = h(0) = zeros
    hipMemsetAsync(hT + (size_t)ll * (HRING_ * 32 * 512), 0, 32 * 512 * 2, stream);
  hipMemsetAsync(xT, 0x7F, xT_bytes, stream);

  { int n = G3H_ * K0_; convert_bf16<<<(n + 255) / 256, 256, 0, stream>>>(wih0, wih0_b, n); }
  { int n = CV_ * H_;   convert_bf16<<<(n + 255) / 256, 256, 0, stream>>>(fcw, fcw_b, n); }
  { int n = NBF_ * WSZ_;
    prep_wfrag<<<(n + 255) / 256, 256, 0, stream>>>(whh0, whhr, wihr, wsw, n); }
  { int n = NBF_ * 64;
    prep_bias<<<(n + 255) / 256, 256, 0, stream>>>(bhh0, bihr, bhhr, bias_sw, n); }

  emb_kernel<<<BT_, 64, 0, stream>>>(note, chord, ctab, ntab, x0);

  // fused: 160 GRU blocks + 6144 xp-GEMM blocks (chunk-major) in one launch
  gru_fused<<<NBF_ + GXB_, 256, 0, stream>>>(xp, wsw, bias_sw, hT, xT, xout, cprog,
                                             x0, wih0_b, bih0, gprog);

  // FC: out = xout @ fcw^T + fcb   (overwrites the ring scratch in d_out)
  gemm_bt<<<dim3((CV_ + 63) / 64, BT_ / 64), 256, 0, stream>>>(
      xout, fcw_b, fcb, out, BT_, CV_, H_, 0);
}